// Round 4
// baseline (3878.831 us; speedup 1.0000x reference)
//
#include <hip/hip_runtime.h>
#include <hip/hip_bf16.h>
#include <math.h>

#define L_SEQ 512
#define N_B   64
#define H_D   512
#define M_TOT (L_SEQ * N_B)   // 32768

// Canary: bf16 NaN pattern. tanh outputs are in (-1,1) and h_init is finite,
// so f2bf never produces 0x7FC0 -> a data dword never equals 0x7FC07FC0.
#define CANI ((int)0x7FC07FC0)

typedef unsigned short u16;
typedef unsigned long long u64;
typedef __attribute__((ext_vector_type(8))) short short8;
typedef __attribute__((ext_vector_type(4))) float f32x4;
typedef __attribute__((ext_vector_type(4))) int i32x4;
typedef __attribute__((ext_vector_type(2))) int i32x2;

__device__ __forceinline__ u16 f2bf(float f) {
    unsigned int u = __builtin_bit_cast(unsigned int, f);
    u = u + 0x7fffu + ((u >> 16) & 1u);
    return (u16)(u >> 16);
}

__device__ __forceinline__ float fast_tanh(float x) {
    float e = __expf(2.0f * x);
    return 1.0f - 2.0f / (e + 1.0f);
}

// 16 device-coherent 16B loads (the poll IS the data fetch) + drain.
#define LD16P(f, p)                                                         \
  asm volatile(                                                             \
    "global_load_dwordx4 %0, %16, off sc1\n\t"                              \
    "global_load_dwordx4 %1, %16, off offset:64 sc1\n\t"                    \
    "global_load_dwordx4 %2, %16, off offset:128 sc1\n\t"                   \
    "global_load_dwordx4 %3, %16, off offset:192 sc1\n\t"                   \
    "global_load_dwordx4 %4, %16, off offset:256 sc1\n\t"                   \
    "global_load_dwordx4 %5, %16, off offset:320 sc1\n\t"                   \
    "global_load_dwordx4 %6, %16, off offset:384 sc1\n\t"                   \
    "global_load_dwordx4 %7, %16, off offset:448 sc1\n\t"                   \
    "global_load_dwordx4 %8, %16, off offset:512 sc1\n\t"                   \
    "global_load_dwordx4 %9, %16, off offset:576 sc1\n\t"                   \
    "global_load_dwordx4 %10, %16, off offset:640 sc1\n\t"                  \
    "global_load_dwordx4 %11, %16, off offset:704 sc1\n\t"                  \
    "global_load_dwordx4 %12, %16, off offset:768 sc1\n\t"                  \
    "global_load_dwordx4 %13, %16, off offset:832 sc1\n\t"                  \
    "global_load_dwordx4 %14, %16, off offset:896 sc1\n\t"                  \
    "global_load_dwordx4 %15, %16, off offset:960 sc1\n\t"                  \
    "s_waitcnt vmcnt(0)"                                                    \
    : "=&v"(f[0]), "=&v"(f[1]), "=&v"(f[2]), "=&v"(f[3]),                   \
      "=&v"(f[4]), "=&v"(f[5]), "=&v"(f[6]), "=&v"(f[7]),                   \
      "=&v"(f[8]), "=&v"(f[9]), "=&v"(f[10]), "=&v"(f[11]),                 \
      "=&v"(f[12]), "=&v"(f[13]), "=&v"(f[14]), "=&v"(f[15])                \
    : "v"(p) : "memory")

// 32 coherent loads from two rows (layer 1), single drain
#define LD16X2P(f, g, p0, p1)                                               \
  asm volatile(                                                             \
    "global_load_dwordx4 %0, %32, off sc1\n\t"                              \
    "global_load_dwordx4 %16, %33, off sc1\n\t"                             \
    "global_load_dwordx4 %1, %32, off offset:64 sc1\n\t"                    \
    "global_load_dwordx4 %17, %33, off offset:64 sc1\n\t"                   \
    "global_load_dwordx4 %2, %32, off offset:128 sc1\n\t"                   \
    "global_load_dwordx4 %18, %33, off offset:128 sc1\n\t"                  \
    "global_load_dwordx4 %3, %32, off offset:192 sc1\n\t"                   \
    "global_load_dwordx4 %19, %33, off offset:192 sc1\n\t"                  \
    "global_load_dwordx4 %4, %32, off offset:256 sc1\n\t"                   \
    "global_load_dwordx4 %20, %33, off offset:256 sc1\n\t"                  \
    "global_load_dwordx4 %5, %32, off offset:320 sc1\n\t"                   \
    "global_load_dwordx4 %21, %33, off offset:320 sc1\n\t"                  \
    "global_load_dwordx4 %6, %32, off offset:384 sc1\n\t"                   \
    "global_load_dwordx4 %22, %33, off offset:384 sc1\n\t"                  \
    "global_load_dwordx4 %7, %32, off offset:448 sc1\n\t"                   \
    "global_load_dwordx4 %23, %33, off offset:448 sc1\n\t"                  \
    "global_load_dwordx4 %8, %32, off offset:512 sc1\n\t"                   \
    "global_load_dwordx4 %24, %33, off offset:512 sc1\n\t"                  \
    "global_load_dwordx4 %9, %32, off offset:576 sc1\n\t"                   \
    "global_load_dwordx4 %25, %33, off offset:576 sc1\n\t"                  \
    "global_load_dwordx4 %10, %32, off offset:640 sc1\n\t"                  \
    "global_load_dwordx4 %26, %33, off offset:640 sc1\n\t"                  \
    "global_load_dwordx4 %11, %32, off offset:704 sc1\n\t"                  \
    "global_load_dwordx4 %27, %33, off offset:704 sc1\n\t"                  \
    "global_load_dwordx4 %12, %32, off offset:768 sc1\n\t"                  \
    "global_load_dwordx4 %28, %33, off offset:768 sc1\n\t"                  \
    "global_load_dwordx4 %13, %32, off offset:832 sc1\n\t"                  \
    "global_load_dwordx4 %29, %33, off offset:832 sc1\n\t"                  \
    "global_load_dwordx4 %14, %32, off offset:896 sc1\n\t"                  \
    "global_load_dwordx4 %30, %33, off offset:896 sc1\n\t"                  \
    "global_load_dwordx4 %15, %32, off offset:960 sc1\n\t"                  \
    "global_load_dwordx4 %31, %33, off offset:960 sc1\n\t"                  \
    "s_waitcnt vmcnt(0)"                                                    \
    : "=&v"(f[0]), "=&v"(f[1]), "=&v"(f[2]), "=&v"(f[3]),                   \
      "=&v"(f[4]), "=&v"(f[5]), "=&v"(f[6]), "=&v"(f[7]),                   \
      "=&v"(f[8]), "=&v"(f[9]), "=&v"(f[10]), "=&v"(f[11]),                 \
      "=&v"(f[12]), "=&v"(f[13]), "=&v"(f[14]), "=&v"(f[15]),               \
      "=&v"(g[0]), "=&v"(g[1]), "=&v"(g[2]), "=&v"(g[3]),                   \
      "=&v"(g[4]), "=&v"(g[5]), "=&v"(g[6]), "=&v"(g[7]),                   \
      "=&v"(g[8]), "=&v"(g[9]), "=&v"(g[10]), "=&v"(g[11]),                 \
      "=&v"(g[12]), "=&v"(g[13]), "=&v"(g[14]), "=&v"(g[15])                \
    : "v"(p0), "v"(p1) : "memory")

#define SEGOK(v) (((v)[0] != CANI) & ((v)[1] != CANI) & ((v)[2] != CANI) & ((v)[3] != CANI))

// K-permutation within each 32-col block: storage position j holds
// canonical column perm32(j). Lets a layer-0 lane store its 8 output bf16
// as ONE dwordx4.
__device__ __host__ __forceinline__ int perm32(int j) {
    return (((j >> 3) & 3) << 2) | (j & 3) | (((j >> 2) & 1) << 4);
}

// ---- prep: fp32->bf16 conversions, bias sums ----
__global__ void k_prep(const float* __restrict__ x,
                       const float* __restrict__ w0ih, const float* __restrict__ w0hh,
                       const float* __restrict__ b0i,  const float* __restrict__ b0h,
                       const float* __restrict__ w1ih, const float* __restrict__ w1hh,
                       const float* __restrict__ b1i,  const float* __restrict__ b1h,
                       u16* __restrict__ xb,
                       u16* __restrict__ w0ihb, u16* __restrict__ w0hhb,
                       u16* __restrict__ w1ihb, u16* __restrict__ w1hhb,
                       float* __restrict__ bias0, float* __restrict__ bias1)
{
    const int stride = gridDim.x * blockDim.x;
    const int tid = blockIdx.x * blockDim.x + threadIdx.x;
    for (int i = tid; i < M_TOT * H_D / 4; i += stride) {
        const float4 v = ((const float4*)x)[i];
        ushort4 o;
        o.x = f2bf(v.x); o.y = f2bf(v.y); o.z = f2bf(v.z); o.w = f2bf(v.w);
        ((ushort4*)xb)[i] = o;
    }
    for (int i = tid; i < H_D * H_D; i += stride) {
        const int p  = i & (H_D - 1);
        const int pc = (i & ~(H_D - 1)) | (p & ~31) | perm32(p & 31);
        w0ihb[i] = f2bf(w0ih[i]);
        w0hhb[i] = f2bf(w0hh[pc]);
        w1ihb[i] = f2bf(w1ih[pc]);
        w1hhb[i] = f2bf(w1hh[i]);
    }
    if (tid < H_D) {
        bias0[tid] = b0i[tid] + b0h[tid];
        bias1[tid] = b1i[tid] + b1h[tid];
    }
}

// ---- canary fill of both h buffers. Runs AFTER k_gemm (h1buf aliases xb)
// and BEFORE k_rec. Normal stores; kernel-end writeback + k_rec's sc1 polls
// (which bypass L2) make them visible. Re-runs every launch (graph replay
// leaves stale real data otherwise).
__global__ void k_init(i32x4* __restrict__ h0c, i32x4* __restrict__ h1c, int n16)
{
    const int stride = gridDim.x * blockDim.x;
    const i32x4 c = {CANI, CANI, CANI, CANI};
    for (int i = blockIdx.x * blockDim.x + threadIdx.x; i < n16; i += stride) {
        h0c[i] = c;
        h1c[i] = c;
    }
}

// ---- big parallel GEMM: out[M,512] = A @ W^T + bias (bf16 MFMA) ----
__global__ __launch_bounds__(256)
void k_gemm(const u16* __restrict__ A, const u16* __restrict__ W,
            const float* __restrict__ bias, float* __restrict__ out)
{
    __shared__ u16 As[128][40];
    __shared__ u16 Ws[128][40];
    const int m0 = blockIdx.x * 128;
    const int n0 = blockIdx.y * 128;
    const int tid = threadIdx.x;
    const int w = tid >> 6, l = tid & 63, q = l >> 4, lr = l & 15;
    const int mw = (w >> 1) * 64, nw = (w & 1) * 64;
    const int skg = (tid & 3) * 8;
    const int smr = tid >> 2;

    f32x4 acc[4][4];
    #pragma unroll
    for (int i = 0; i < 4; ++i)
        #pragma unroll
        for (int j = 0; j < 4; ++j)
            acc[i][j] = (f32x4){0.f, 0.f, 0.f, 0.f};

    for (int kk = 0; kk < H_D; kk += 32) {
        *(uint4*)&As[smr][skg]      = *(const uint4*)(A + (size_t)(m0 + smr) * H_D + kk + skg);
        *(uint4*)&As[smr + 64][skg] = *(const uint4*)(A + (size_t)(m0 + smr + 64) * H_D + kk + skg);
        *(uint4*)&Ws[smr][skg]      = *(const uint4*)(W + (size_t)(n0 + smr) * H_D + kk + skg);
        *(uint4*)&Ws[smr + 64][skg] = *(const uint4*)(W + (size_t)(n0 + smr + 64) * H_D + kk + skg);
        __syncthreads();
        short8 af[4], bf[4];
        #pragma unroll
        for (int rt = 0; rt < 4; ++rt) af[rt] = *(const short8*)&As[mw + rt*16 + lr][q*8];
        #pragma unroll
        for (int nt = 0; nt < 4; ++nt) bf[nt] = *(const short8*)&Ws[nw + nt*16 + lr][q*8];
        #pragma unroll
        for (int rt = 0; rt < 4; ++rt)
            #pragma unroll
            for (int nt = 0; nt < 4; ++nt)
                acc[rt][nt] = __builtin_amdgcn_mfma_f32_16x16x32_bf16(af[rt], bf[nt], acc[rt][nt], 0, 0, 0);
        __syncthreads();
    }
    #pragma unroll
    for (int nt = 0; nt < 4; ++nt) {
        const int col = n0 + nw + nt*16 + lr;
        const float bv = bias[col];
        #pragma unroll
        for (int rt = 0; rt < 4; ++rt) {
            #pragma unroll
            for (int r = 0; r < 4; ++r) {
                const int row = m0 + mw + rt*16 + q*4 + r;
                out[(size_t)row * H_D + col] = acc[rt][nt][r] + bv;
            }
        }
    }
}

// ---- fused 2-layer recurrence: canary-in-data dataflow, NO flags/barriers.
// blocks 0..15: layer 0 (32-col slices).  blocks 16..47: layer 1 (16-col slices).
// hbuf slot s holds h[t = s-1]; slot 0 = h_init.
// Producers store sc1 and move on (no drain). Consumers poll the data itself
// with sc1 loads until every dword != canary; detected values are already in
// the MFMA input registers. All h stores are >= dword-wide so no torn dwords.
__global__ __launch_bounds__(256, 1)
void k_rec_fused(const u16* __restrict__ Whh0, const u16* __restrict__ Wih1,
                 const u16* __restrict__ Whh1,
                 const float* __restrict__ h_init,
                 const float* __restrict__ pre0,
                 const float* __restrict__ bias1,
                 u16* __restrict__ h0buf, u16* __restrict__ h1buf,
                 float* __restrict__ out, float* __restrict__ hn)
{
    // One-shot agent-scope acquire: invalidate L1/L2 so cached reads of pre0/
    // weights can't be stale across graph replays.
    (void)__hip_atomic_load((const int*)h0buf, __ATOMIC_ACQUIRE, __HIP_MEMORY_SCOPE_AGENT);

    const int tid = threadIdx.x;
    const int w = tid >> 6, l = tid & 63, q = l >> 4, lr = l & 15;
    const int r0 = w * 16;
    const int m = r0 + lr;

    if (blockIdx.x < 16) {
        // ================= layer 0: 32 columns =================
        const int c = blockIdx.x;
        const int nbase = c * 32;
        short8 breg[16][2];
        #pragma unroll
        for (int kt = 0; kt < 16; ++kt)
            #pragma unroll
            for (int nt = 0; nt < 2; ++nt)
                breg[kt][nt] = *(const short8*)(Whh0 + (size_t)(nbase + nt*16 + lr) * H_D + kt*32 + q*8);

        // stage 0: publish h_init slot 0 (16 rows x 32 positions, permuted),
        // paired-dword stores (no sub-dword writes -> canary-safe).
        #pragma unroll
        for (int j = 0; j < 4; ++j) {
            int idx = l * 8 + j * 2;
            int row = r0 + (idx >> 5);
            int pos = idx & 31;
            unsigned lo = f2bf(h_init[row * H_D + nbase + perm32(pos)]);
            unsigned hi = f2bf(h_init[row * H_D + nbase + perm32(pos + 1)]);
            unsigned dv = lo | (hi << 16);
            u16* dp = h0buf + (size_t)row * H_D + nbase + pos;
            asm volatile("global_store_dword %0, %1, off sc1"
                         :: "v"(dp), "v"(dv) : "memory");
        }

        for (int t = 0; t < L_SEQ; ++t) {
            // pre-activation init (independent of h): one float4 x2, cached
            const float* pt = pre0 + (size_t)t * (N_B * H_D)
                            + (size_t)(r0 + lr) * H_D + nbase + q*4;
            f32x4 acc0a = *(const f32x4*)pt;
            f32x4 acc1a = *(const f32x4*)(pt + 16);
            f32x4 acc0b = (f32x4){0.f,0.f,0.f,0.f};
            f32x4 acc1b = (f32x4){0.f,0.f,0.f,0.f};
            f32x4 acc0c = (f32x4){0.f,0.f,0.f,0.f};
            f32x4 acc1c = (f32x4){0.f,0.f,0.f,0.f};
            f32x4 acc0d = (f32x4){0.f,0.f,0.f,0.f};
            f32x4 acc1d = (f32x4){0.f,0.f,0.f,0.f};

            // poll = load h0[t] row m until all 16 segments are real data
            const u16* hs = h0buf + ((size_t)t * N_B + m) * H_D + q*8;
            i32x4 f[16];
            while (true) {
                LD16P(f, hs);
                int ok = 1;
                #pragma unroll
                for (int i = 0; i < 16; ++i) ok &= SEGOK(f[i]);
                if (__all(ok)) break;
            }

            #pragma unroll
            for (int kt = 0; kt < 16; kt += 4) {
                acc0a = __builtin_amdgcn_mfma_f32_16x16x32_bf16(breg[kt][0],   __builtin_bit_cast(short8, f[kt]),   acc0a, 0, 0, 0);
                acc1a = __builtin_amdgcn_mfma_f32_16x16x32_bf16(breg[kt][1],   __builtin_bit_cast(short8, f[kt]),   acc1a, 0, 0, 0);
                acc0b = __builtin_amdgcn_mfma_f32_16x16x32_bf16(breg[kt+1][0], __builtin_bit_cast(short8, f[kt+1]), acc0b, 0, 0, 0);
                acc1b = __builtin_amdgcn_mfma_f32_16x16x32_bf16(breg[kt+1][1], __builtin_bit_cast(short8, f[kt+1]), acc1b, 0, 0, 0);
                acc0c = __builtin_amdgcn_mfma_f32_16x16x32_bf16(breg[kt+2][0], __builtin_bit_cast(short8, f[kt+2]), acc0c, 0, 0, 0);
                acc1c = __builtin_amdgcn_mfma_f32_16x16x32_bf16(breg[kt+2][1], __builtin_bit_cast(short8, f[kt+2]), acc1c, 0, 0, 0);
                acc0d = __builtin_amdgcn_mfma_f32_16x16x32_bf16(breg[kt+3][0], __builtin_bit_cast(short8, f[kt+3]), acc0d, 0, 0, 0);
                acc1d = __builtin_amdgcn_mfma_f32_16x16x32_bf16(breg[kt+3][1], __builtin_bit_cast(short8, f[kt+3]), acc1d, 0, 0, 0);
            }
            float v0[4], v1[4];
            #pragma unroll
            for (int r = 0; r < 4; ++r) {
                v0[r] = fast_tanh((acc0a[r] + acc0b[r]) + (acc0c[r] + acc0d[r]));
                v1[r] = fast_tanh((acc1a[r] + acc1b[r]) + (acc1c[r] + acc1d[r]));
            }
            // permuted pack: positions q*8+s hold cols q*4+(s&3)+16*(s>>2)
            i32x4 dd;
            dd[0] = (int)((unsigned)f2bf(v0[0]) | ((unsigned)f2bf(v0[1]) << 16));
            dd[1] = (int)((unsigned)f2bf(v0[2]) | ((unsigned)f2bf(v0[3]) << 16));
            dd[2] = (int)((unsigned)f2bf(v1[0]) | ((unsigned)f2bf(v1[1]) << 16));
            dd[3] = (int)((unsigned)f2bf(v1[2]) | ((unsigned)f2bf(v1[3]) << 16));
            u16* hd = h0buf + (size_t)(t+1) * (N_B * H_D)
                    + (size_t)(r0 + lr) * H_D + nbase + q*8;
            asm volatile(
                "global_store_dwordx4 %1, %0, off sc1"
                :: "v"(dd), "v"(hd) : "memory");
            // no drain, no flag, no barrier — straight to next step

            if (t == L_SEQ - 1) {
                f32x4 o0 = {v0[0], v0[1], v0[2], v0[3]};
                f32x4 o1 = {v1[0], v1[1], v1[2], v1[3]};
                *(f32x4*)(hn + (size_t)(r0 + lr) * H_D + nbase + q*4)      = o0;
                *(f32x4*)(hn + (size_t)(r0 + lr) * H_D + nbase + 16 + q*4) = o1;
            }
        }
    } else {
        // ================= layer 1: 16 columns =================
        const int c = blockIdx.x - 16;
        const int nbase = c * 16;
        short8 bregI[16], bregH[16];
        #pragma unroll
        for (int kt = 0; kt < 16; ++kt) {
            bregI[kt] = *(const short8*)(Wih1 + (size_t)(nbase + lr) * H_D + kt*32 + q*8);
            bregH[kt] = *(const short8*)(Whh1 + (size_t)(nbase + lr) * H_D + kt*32 + q*8);
        }
        const f32x4 bv4 = *(const f32x4*)(bias1 + nbase + q*4);

        const float* hi1 = h_init + N_B * H_D;
        #pragma unroll
        for (int j = 0; j < 2; ++j) {
            int idx = l * 4 + j * 2;
            int row = r0 + (idx >> 4);
            int col = nbase + (idx & 15);
            unsigned lo = f2bf(hi1[row * H_D + col]);
            unsigned hi = f2bf(hi1[row * H_D + col + 1]);
            unsigned dv = lo | (hi << 16);
            u16* dp = h1buf + (size_t)row * H_D + col;
            asm volatile("global_store_dword %0, %1, off sc1"
                         :: "v"(dp), "v"(dv) : "memory");
        }

        for (int t = 0; t < L_SEQ; ++t) {
            const u16* p0 = h0buf + ((size_t)(t+1) * N_B + m) * H_D + q*8;
            const u16* p1 = h1buf + ((size_t)t     * N_B + m) * H_D + q*8;
            i32x4 f[16], g[16];
            while (true) {
                LD16X2P(f, g, p0, p1);
                int ok = 1;
                #pragma unroll
                for (int i = 0; i < 16; ++i) ok &= SEGOK(f[i]) & SEGOK(g[i]);
                if (__all(ok)) break;
            }
            f32x4 accA = bv4;
            f32x4 accB = (f32x4){0.f,0.f,0.f,0.f};
            f32x4 accC = (f32x4){0.f,0.f,0.f,0.f};
            f32x4 accD = (f32x4){0.f,0.f,0.f,0.f};
            #pragma unroll
            for (int kt = 0; kt < 16; kt += 2) {
                accA = __builtin_amdgcn_mfma_f32_16x16x32_bf16(bregI[kt],   __builtin_bit_cast(short8, f[kt]),   accA, 0, 0, 0);
                accB = __builtin_amdgcn_mfma_f32_16x16x32_bf16(bregH[kt],   __builtin_bit_cast(short8, g[kt]),   accB, 0, 0, 0);
                accC = __builtin_amdgcn_mfma_f32_16x16x32_bf16(bregI[kt+1], __builtin_bit_cast(short8, f[kt+1]), accC, 0, 0, 0);
                accD = __builtin_amdgcn_mfma_f32_16x16x32_bf16(bregH[kt+1], __builtin_bit_cast(short8, g[kt+1]), accD, 0, 0, 0);
            }
            float v[4];
            #pragma unroll
            for (int r = 0; r < 4; ++r)
                v[r] = fast_tanh((accA[r] + accB[r]) + (accC[r] + accD[r]));
            i32x2 d;
            d[0] = (int)((unsigned)f2bf(v[0]) | ((unsigned)f2bf(v[1]) << 16));
            d[1] = (int)((unsigned)f2bf(v[2]) | ((unsigned)f2bf(v[3]) << 16));
            u16* hd = h1buf + (size_t)(t+1) * (N_B * H_D)
                    + (size_t)(r0 + lr) * H_D + nbase + q*4;
            asm volatile(
                "global_store_dwordx2 %1, %0, off sc1"
                :: "v"(d), "v"(hd) : "memory");

            f32x4 ov = {v[0], v[1], v[2], v[3]};
            *(f32x4*)(out + (size_t)t * (N_B * H_D)
                      + (size_t)(r0 + lr) * H_D + nbase + q*4) = ov;
            if (t == L_SEQ - 1)
                *(f32x4*)(hn + (size_t)(N_B + r0 + lr) * H_D + nbase + q*4) = ov;
        }
    }
}

extern "C" void kernel_launch(void* const* d_in, const int* in_sizes, int n_in,
                              void* d_out, int out_size, void* d_ws, size_t ws_size,
                              hipStream_t stream)
{
    (void)in_sizes; (void)n_in; (void)out_size; (void)ws_size;
    const float* x    = (const float*)d_in[0];
    const float* h0   = (const float*)d_in[1];
    const float* w0ih = (const float*)d_in[2];
    const float* w0hh = (const float*)d_in[3];
    const float* b0i  = (const float*)d_in[4];
    const float* b0h  = (const float*)d_in[5];
    const float* w1ih = (const float*)d_in[6];
    const float* w1hh = (const float*)d_in[7];
    const float* b1i  = (const float*)d_in[8];
    const float* b1h  = (const float*)d_in[9];
    float* out = (float*)d_out;
    float* hn  = out + (size_t)M_TOT * H_D;

    char* ws = (char*)d_ws;
    size_t off = 0;
    u16* w0ihb = (u16*)(ws + off);   off += (size_t)H_D * H_D * 2;
    u16* w0hhb = (u16*)(ws + off);   off += (size_t)H_D * H_D * 2;
    u16* w1ihb = (u16*)(ws + off);   off += (size_t)H_D * H_D * 2;
    u16* w1hhb = (u16*)(ws + off);   off += (size_t)H_D * H_D * 2;
    float* bias0 = (float*)(ws + off); off += H_D * 4;
    float* bias1 = (float*)(ws + off); off += H_D * 4;
    u16* h0buf   = (u16*)(ws + off);   off += (size_t)(L_SEQ + 1) * N_B * H_D * 2;
    float* pre0  = (float*)(ws + off); off += (size_t)M_TOT * H_D * 4;
    u16* h1buf   = (u16*)(ws + off);   off += (size_t)(L_SEQ + 1) * N_B * H_D * 2;
    u16* xb      = h1buf;   // xb dead after k_gemm; aliases h1buf

    const int n16 = (L_SEQ + 1) * N_B * H_D * 2 / 16;  // 16B chunks per h buffer

    k_prep<<<2048, 256, 0, stream>>>(x, w0ih, w0hh, b0i, b0h, w1ih, w1hh, b1i, b1h,
                                     xb, w0ihb, w0hhb, w1ihb, w1hhb,
                                     bias0, bias1);
    k_gemm<<<dim3(M_TOT/128, H_D/128), 256, 0, stream>>>(xb, w0ihb, bias0, pre0);
    // canary fill AFTER gemm (h1buf aliased xb) and BEFORE recurrence
    k_init<<<2048, 256, 0, stream>>>((i32x4*)h0buf, (i32x4*)h1buf, n16);
    k_rec_fused<<<48, 256, 0, stream>>>(w0hhb, w1ihb, w1hhb, h0, pre0, bias1,
                                        h0buf, h1buf, out, hn);
}

// Round 6
// 2767.824 us; speedup vs baseline: 1.4014x; 1.4014x over previous
//
#include <hip/hip_runtime.h>
#include <hip/hip_bf16.h>
#include <math.h>

#define L_SEQ 512
#define N_B   64
#define H_D   512
#define M_TOT (L_SEQ * N_B)   // 32768
#define FSTRIDE 16            // one flag word per 64B line

typedef unsigned short u16;
typedef unsigned long long u64;
typedef __attribute__((ext_vector_type(8))) short short8;
typedef __attribute__((ext_vector_type(4))) float f32x4;
typedef __attribute__((ext_vector_type(4))) int i32x4;
typedef __attribute__((ext_vector_type(2))) int i32x2;

__device__ __forceinline__ u16 f2bf(float f) {
    unsigned int u = __builtin_bit_cast(unsigned int, f);
    u = u + 0x7fffu + ((u >> 16) & 1u);
    return (u16)(u >> 16);
}

__device__ __forceinline__ float fast_tanh(float x) {
    float e = __expf(2.0f * x);
    return 1.0f - 2.0f / (e + 1.0f);
}

__device__ __forceinline__ void st_h(u16* p, u16 v) {
    __hip_atomic_store(p, v, __ATOMIC_RELAXED, __HIP_MEMORY_SCOPE_AGENT);
}
__device__ __forceinline__ void st_flag(int* p, int v) {
    __hip_atomic_store(p, v, __ATOMIC_RELAXED, __HIP_MEMORY_SCOPE_AGENT);
}

// Flag layout: one word per (block, wave), each on its own 64B line.
// flags0: 16 blocks x 4 waves = 64 words. flags1: 32 x 4 = 128 words.
// Wave-granular flags let every consumer wave proceed as soon as the
// MATCHING producer waves (same row range) have published -> no barriers
// in the recurrence loop at all, and producer waves are decoupled.

// 16 CACHED 16B loads (512B of one row) + single drain.
// Correctness of cached loads: h slots are write-once (sc1 write-through to
// the coherence point), a consumer first touches a slot's lines only after
// the per-wave flag trips, and slot lines are 64B-pure. Entry acquire fence
// kills pre-launch stale lines (incl. the xb/h1buf alias from k_gemm).
#define LD16(f, p)                                                          \
  asm volatile(                                                             \
    "global_load_dwordx4 %0, %16, off\n\t"                                  \
    "global_load_dwordx4 %1, %16, off offset:64\n\t"                        \
    "global_load_dwordx4 %2, %16, off offset:128\n\t"                       \
    "global_load_dwordx4 %3, %16, off offset:192\n\t"                       \
    "global_load_dwordx4 %4, %16, off offset:256\n\t"                       \
    "global_load_dwordx4 %5, %16, off offset:320\n\t"                       \
    "global_load_dwordx4 %6, %16, off offset:384\n\t"                       \
    "global_load_dwordx4 %7, %16, off offset:448\n\t"                       \
    "global_load_dwordx4 %8, %16, off offset:512\n\t"                       \
    "global_load_dwordx4 %9, %16, off offset:576\n\t"                       \
    "global_load_dwordx4 %10, %16, off offset:640\n\t"                      \
    "global_load_dwordx4 %11, %16, off offset:704\n\t"                      \
    "global_load_dwordx4 %12, %16, off offset:768\n\t"                      \
    "global_load_dwordx4 %13, %16, off offset:832\n\t"                      \
    "global_load_dwordx4 %14, %16, off offset:896\n\t"                      \
    "global_load_dwordx4 %15, %16, off offset:960\n\t"                      \
    "s_waitcnt vmcnt(0)"                                                    \
    : "=&v"(f[0]), "=&v"(f[1]), "=&v"(f[2]), "=&v"(f[3]),                   \
      "=&v"(f[4]), "=&v"(f[5]), "=&v"(f[6]), "=&v"(f[7]),                   \
      "=&v"(f[8]), "=&v"(f[9]), "=&v"(f[10]), "=&v"(f[11]),                 \
      "=&v"(f[12]), "=&v"(f[13]), "=&v"(f[14]), "=&v"(f[15])                \
    : "v"(p) : "memory")

#define LD16X2(f, g, p0, p1)                                                \
  asm volatile(                                                             \
    "global_load_dwordx4 %0, %32, off\n\t"                                  \
    "global_load_dwordx4 %16, %33, off\n\t"                                 \
    "global_load_dwordx4 %1, %32, off offset:64\n\t"                        \
    "global_load_dwordx4 %17, %33, off offset:64\n\t"                       \
    "global_load_dwordx4 %2, %32, off offset:128\n\t"                       \
    "global_load_dwordx4 %18, %33, off offset:128\n\t"                      \
    "global_load_dwordx4 %3, %32, off offset:192\n\t"                       \
    "global_load_dwordx4 %19, %33, off offset:192\n\t"                      \
    "global_load_dwordx4 %4, %32, off offset:256\n\t"                       \
    "global_load_dwordx4 %20, %33, off offset:256\n\t"                      \
    "global_load_dwordx4 %5, %32, off offset:320\n\t"                       \
    "global_load_dwordx4 %21, %33, off offset:320\n\t"                      \
    "global_load_dwordx4 %6, %32, off offset:384\n\t"                       \
    "global_load_dwordx4 %22, %33, off offset:384\n\t"                      \
    "global_load_dwordx4 %7, %32, off offset:448\n\t"                       \
    "global_load_dwordx4 %23, %33, off offset:448\n\t"                      \
    "global_load_dwordx4 %8, %32, off offset:512\n\t"                       \
    "global_load_dwordx4 %24, %33, off offset:512\n\t"                      \
    "global_load_dwordx4 %9, %32, off offset:576\n\t"                       \
    "global_load_dwordx4 %25, %33, off offset:576\n\t"                      \
    "global_load_dwordx4 %10, %32, off offset:640\n\t"                      \
    "global_load_dwordx4 %26, %33, off offset:640\n\t"                      \
    "global_load_dwordx4 %11, %32, off offset:704\n\t"                      \
    "global_load_dwordx4 %27, %33, off offset:704\n\t"                      \
    "global_load_dwordx4 %12, %32, off offset:768\n\t"                      \
    "global_load_dwordx4 %28, %33, off offset:768\n\t"                      \
    "global_load_dwordx4 %13, %32, off offset:832\n\t"                      \
    "global_load_dwordx4 %29, %33, off offset:832\n\t"                      \
    "global_load_dwordx4 %14, %32, off offset:896\n\t"                      \
    "global_load_dwordx4 %30, %33, off offset:896\n\t"                      \
    "global_load_dwordx4 %15, %32, off offset:960\n\t"                      \
    "global_load_dwordx4 %31, %33, off offset:960\n\t"                      \
    "s_waitcnt vmcnt(0)"                                                    \
    : "=&v"(f[0]), "=&v"(f[1]), "=&v"(f[2]), "=&v"(f[3]),                   \
      "=&v"(f[4]), "=&v"(f[5]), "=&v"(f[6]), "=&v"(f[7]),                   \
      "=&v"(f[8]), "=&v"(f[9]), "=&v"(f[10]), "=&v"(f[11]),                 \
      "=&v"(f[12]), "=&v"(f[13]), "=&v"(f[14]), "=&v"(f[15]),               \
      "=&v"(g[0]), "=&v"(g[1]), "=&v"(g[2]), "=&v"(g[3]),                   \
      "=&v"(g[4]), "=&v"(g[5]), "=&v"(g[6]), "=&v"(g[7]),                   \
      "=&v"(g[8]), "=&v"(g[9]), "=&v"(g[10]), "=&v"(g[11]),                 \
      "=&v"(g[12]), "=&v"(g[13]), "=&v"(g[14]), "=&v"(g[15])                \
    : "v"(p0), "v"(p1) : "memory")

#define WAITVM asm volatile("s_waitcnt vmcnt(0)" ::: "memory")

// K-permutation within each 32-col block: storage position j holds
// canonical column perm32(j). Lets a layer-0 lane store its 8 output bf16
// as ONE dwordx4.
__device__ __host__ __forceinline__ int perm32(int j) {
    return (((j >> 3) & 3) << 2) | (j & 3) | (((j >> 2) & 1) << 4);
}

// ---- prep: fp32->bf16 conversions, bias sums, flag zeroing ----
// w0hhb and w1ihb are stored with their K-dim permuted by perm32 (they
// multiply h0, which is stored position-permuted). w0ihb (k_gemm, canonical
// xb) and w1hhb (multiplies canonical h1buf) stay canonical.
__global__ void k_prep(const float* __restrict__ x,
                       const float* __restrict__ w0ih, const float* __restrict__ w0hh,
                       const float* __restrict__ b0i,  const float* __restrict__ b0h,
                       const float* __restrict__ w1ih, const float* __restrict__ w1hh,
                       const float* __restrict__ b1i,  const float* __restrict__ b1h,
                       u16* __restrict__ xb,
                       u16* __restrict__ w0ihb, u16* __restrict__ w0hhb,
                       u16* __restrict__ w1ihb, u16* __restrict__ w1hhb,
                       float* __restrict__ bias0, float* __restrict__ bias1,
                       int* __restrict__ flags)
{
    const int stride = gridDim.x * blockDim.x;
    const int tid = blockIdx.x * blockDim.x + threadIdx.x;
    for (int i = tid; i < M_TOT * H_D / 4; i += stride) {
        const float4 v = ((const float4*)x)[i];
        ushort4 o;
        o.x = f2bf(v.x); o.y = f2bf(v.y); o.z = f2bf(v.z); o.w = f2bf(v.w);
        ((ushort4*)xb)[i] = o;
    }
    for (int i = tid; i < H_D * H_D; i += stride) {
        const int p  = i & (H_D - 1);
        const int pc = (i & ~(H_D - 1)) | (p & ~31) | perm32(p & 31);
        w0ihb[i] = f2bf(w0ih[i]);
        w0hhb[i] = f2bf(w0hh[pc]);
        w1ihb[i] = f2bf(w1ih[pc]);
        w1hhb[i] = f2bf(w1hh[i]);
    }
    if (tid < H_D) {
        bias0[tid] = b0i[tid] + b0h[tid];
        bias1[tid] = b1i[tid] + b1h[tid];
    }
    if (tid < 192 * FSTRIDE) flags[tid] = 0;   // 192 per-(block,wave) flags
}

// ---- big parallel GEMM: out[M,512] = A @ W^T + bias (bf16 MFMA) ----
__global__ __launch_bounds__(256)
void k_gemm(const u16* __restrict__ A, const u16* __restrict__ W,
            const float* __restrict__ bias, float* __restrict__ out)
{
    __shared__ u16 As[128][40];
    __shared__ u16 Ws[128][40];
    const int m0 = blockIdx.x * 128;
    const int n0 = blockIdx.y * 128;
    const int tid = threadIdx.x;
    const int w = tid >> 6, l = tid & 63, q = l >> 4, lr = l & 15;
    const int mw = (w >> 1) * 64, nw = (w & 1) * 64;
    const int skg = (tid & 3) * 8;
    const int smr = tid >> 2;

    f32x4 acc[4][4];
    #pragma unroll
    for (int i = 0; i < 4; ++i)
        #pragma unroll
        for (int j = 0; j < 4; ++j)
            acc[i][j] = (f32x4){0.f, 0.f, 0.f, 0.f};

    for (int kk = 0; kk < H_D; kk += 32) {
        *(uint4*)&As[smr][skg]      = *(const uint4*)(A + (size_t)(m0 + smr) * H_D + kk + skg);
        *(uint4*)&As[smr + 64][skg] = *(const uint4*)(A + (size_t)(m0 + smr + 64) * H_D + kk + skg);
        *(uint4*)&Ws[smr][skg]      = *(const uint4*)(W + (size_t)(n0 + smr) * H_D + kk + skg);
        *(uint4*)&Ws[smr + 64][skg] = *(const uint4*)(W + (size_t)(n0 + smr + 64) * H_D + kk + skg);
        __syncthreads();
        short8 af[4], bf[4];
        #pragma unroll
        for (int rt = 0; rt < 4; ++rt) af[rt] = *(const short8*)&As[mw + rt*16 + lr][q*8];
        #pragma unroll
        for (int nt = 0; nt < 4; ++nt) bf[nt] = *(const short8*)&Ws[nw + nt*16 + lr][q*8];
        #pragma unroll
        for (int rt = 0; rt < 4; ++rt)
            #pragma unroll
            for (int nt = 0; nt < 4; ++nt)
                acc[rt][nt] = __builtin_amdgcn_mfma_f32_16x16x32_bf16(af[rt], bf[nt], acc[rt][nt], 0, 0, 0);
        __syncthreads();
    }
    #pragma unroll
    for (int nt = 0; nt < 4; ++nt) {
        const int col = n0 + nw + nt*16 + lr;
        const float bv = bias[col];
        #pragma unroll
        for (int rt = 0; rt < 4; ++rt) {
            #pragma unroll
            for (int r = 0; r < 4; ++r) {
                const int row = m0 + mw + rt*16 + q*4 + r;
                out[(size_t)row * H_D + col] = acc[rt][nt][r] + bv;
            }
        }
    }
}

// ---- fused 2-layer recurrence, wave-autonomous, NO barriers in the loop ----
// blocks 0..15: layer 0 (32-col slices).  blocks 16..47: layer 1 (16-col).
// hbuf slot s holds h[t = s-1]; slot 0 = h_init.
// Wave w of any consumer reads ONLY rows [16w,16w+16) of a slot, which are
// written ONLY by wave w of each producer block. flags[(c*4+w)*FSTRIDE]
// publishes per-(block,wave) progress, so each wave polls just its matching
// 16 (L0) / 48 (L1) flag words and proceeds independently.
__global__ __launch_bounds__(256, 1)
void k_rec_fused(const u16* __restrict__ Whh0, const u16* __restrict__ Wih1,
                 const u16* __restrict__ Whh1,
                 const float* __restrict__ h_init,
                 const float* __restrict__ pre0,
                 const float* __restrict__ bias1,
                 u16* __restrict__ h0buf, u16* __restrict__ h1buf,
                 float* __restrict__ out, float* __restrict__ hn,
                 int* __restrict__ flags0, int* __restrict__ flags1)
{
    // One-shot agent-scope acquire: invalidate L1 + XCD-L2 so no stale
    // pre-launch line can satisfy our cached h loads.
    (void)__hip_atomic_load(flags0, __ATOMIC_ACQUIRE, __HIP_MEMORY_SCOPE_AGENT);

    const int tid = threadIdx.x;
    const int w = tid >> 6, l = tid & 63, q = l >> 4, lr = l & 15;
    const int r0 = w * 16;
    const int m = r0 + lr;

    if (blockIdx.x < 16) {
        // ================= layer 0: 32 columns =================
        const int c = blockIdx.x;
        const int nbase = c * 32;
        short8 breg[16][2];
        #pragma unroll
        for (int kt = 0; kt < 16; ++kt)
            #pragma unroll
            for (int nt = 0; nt < 2; ++nt)
                breg[kt][nt] = *(const short8*)(Whh0 + (size_t)(nbase + nt*16 + lr) * H_D + kt*32 + q*8);

        // stage 0: this wave publishes its 16 rows of slot 0 (permuted)
        #pragma unroll
        for (int j = 0; j < 8; ++j) {
            int idx = l * 8 + j;
            int row = r0 + (idx >> 5);
            int pos = idx & 31;
            st_h(h0buf + (size_t)row * H_D + nbase + pos,
                 f2bf(h_init[row * H_D + nbase + perm32(pos)]));
        }
        WAITVM;
        if (l == 0) st_flag(flags0 + (c*4 + w) * FSTRIDE, 1);

        for (int t = 0; t < L_SEQ; ++t) {
            // pre-activation init (independent of flags): one float4 x2
            const float* pt = pre0 + (size_t)t * (N_B * H_D)
                            + (size_t)(r0 + lr) * H_D + nbase + q*4;
            f32x4 acc0a = *(const f32x4*)pt;
            f32x4 acc1a = *(const f32x4*)(pt + 16);
            f32x4 acc0b = (f32x4){0.f,0.f,0.f,0.f};
            f32x4 acc1b = (f32x4){0.f,0.f,0.f,0.f};
            f32x4 acc0c = (f32x4){0.f,0.f,0.f,0.f};
            f32x4 acc1c = (f32x4){0.f,0.f,0.f,0.f};
            f32x4 acc0d = (f32x4){0.f,0.f,0.f,0.f};
            f32x4 acc1d = (f32x4){0.f,0.f,0.f,0.f};

            // wait for wave w of ALL 16 L0 blocks to have published slot t
            {
                const int* p = flags0 + ((l & 15) * 4 + w) * FSTRIDE;
                while (true) {
                    int v = __hip_atomic_load(p, __ATOMIC_RELAXED, __HIP_MEMORY_SCOPE_AGENT);
                    if (__all(v >= t + 1)) break;
                }
                asm volatile("" ::: "memory");
            }

            const u16* hs = h0buf + ((size_t)t * N_B + m) * H_D + q*8;
            i32x4 f[16];
            LD16(f, hs);
            #pragma unroll
            for (int kt = 0; kt < 16; kt += 4) {
                acc0a = __builtin_amdgcn_mfma_f32_16x16x32_bf16(breg[kt][0],   __builtin_bit_cast(short8, f[kt]),   acc0a, 0, 0, 0);
                acc1a = __builtin_amdgcn_mfma_f32_16x16x32_bf16(breg[kt][1],   __builtin_bit_cast(short8, f[kt]),   acc1a, 0, 0, 0);
                acc0b = __builtin_amdgcn_mfma_f32_16x16x32_bf16(breg[kt+1][0], __builtin_bit_cast(short8, f[kt+1]), acc0b, 0, 0, 0);
                acc1b = __builtin_amdgcn_mfma_f32_16x16x32_bf16(breg[kt+1][1], __builtin_bit_cast(short8, f[kt+1]), acc1b, 0, 0, 0);
                acc0c = __builtin_amdgcn_mfma_f32_16x16x32_bf16(breg[kt+2][0], __builtin_bit_cast(short8, f[kt+2]), acc0c, 0, 0, 0);
                acc1c = __builtin_amdgcn_mfma_f32_16x16x32_bf16(breg[kt+2][1], __builtin_bit_cast(short8, f[kt+2]), acc1c, 0, 0, 0);
                acc0d = __builtin_amdgcn_mfma_f32_16x16x32_bf16(breg[kt+3][0], __builtin_bit_cast(short8, f[kt+3]), acc0d, 0, 0, 0);
                acc1d = __builtin_amdgcn_mfma_f32_16x16x32_bf16(breg[kt+3][1], __builtin_bit_cast(short8, f[kt+3]), acc1d, 0, 0, 0);
            }
            float v0[4], v1[4];
            #pragma unroll
            for (int r = 0; r < 4; ++r) {
                v0[r] = fast_tanh((acc0a[r] + acc0b[r]) + (acc0c[r] + acc0d[r]));
                v1[r] = fast_tanh((acc1a[r] + acc1b[r]) + (acc1c[r] + acc1d[r]));
            }
            // permuted pack: positions q*8+s hold cols q*4+(s&3)+16*(s>>2)
            i32x4 dd;
            dd[0] = (int)((unsigned)f2bf(v0[0]) | ((unsigned)f2bf(v0[1]) << 16));
            dd[1] = (int)((unsigned)f2bf(v0[2]) | ((unsigned)f2bf(v0[3]) << 16));
            dd[2] = (int)((unsigned)f2bf(v1[0]) | ((unsigned)f2bf(v1[1]) << 16));
            dd[3] = (int)((unsigned)f2bf(v1[2]) | ((unsigned)f2bf(v1[3]) << 16));
            u16* hd = h0buf + (size_t)(t+1) * (N_B * H_D)
                    + (size_t)(r0 + lr) * H_D + nbase + q*8;
            asm volatile(
                "global_store_dwordx4 %1, %0, off sc1"
                :: "v"(dd), "v"(hd) : "memory");
            WAITVM;
            if (l == 0) st_flag(flags0 + (c*4 + w) * FSTRIDE, t + 2);

            if (t == L_SEQ - 1) {
                f32x4 o0 = {v0[0], v0[1], v0[2], v0[3]};
                f32x4 o1 = {v1[0], v1[1], v1[2], v1[3]};
                *(f32x4*)(hn + (size_t)(r0 + lr) * H_D + nbase + q*4)      = o0;
                *(f32x4*)(hn + (size_t)(r0 + lr) * H_D + nbase + 16 + q*4) = o1;
            }
        }
    } else {
        // ================= layer 1: 16 columns =================
        const int c = blockIdx.x - 16;
        const int nbase = c * 16;
        short8 bregI[16], bregH[16];
        #pragma unroll
        for (int kt = 0; kt < 16; ++kt) {
            bregI[kt] = *(const short8*)(Wih1 + (size_t)(nbase + lr) * H_D + kt*32 + q*8);
            bregH[kt] = *(const short8*)(Whh1 + (size_t)(nbase + lr) * H_D + kt*32 + q*8);
        }
        const f32x4 bv4 = *(const f32x4*)(bias1 + nbase + q*4);

        const float* hi1 = h_init + N_B * H_D;
        #pragma unroll
        for (int j = 0; j < 4; ++j) {
            int idx = l * 4 + j;
            int row = r0 + (idx >> 4);
            int col = nbase + (idx & 15);
            st_h(h1buf + (size_t)row * H_D + col, f2bf(hi1[row * H_D + col]));
        }
        WAITVM;
        if (l == 0) st_flag(flags1 + (c*4 + w) * FSTRIDE, 1);

        for (int t = 0; t < L_SEQ; ++t) {
            // wait: wave w of all 16 L0 blocks has published slot t+1 (>=t+2)
            //       wave w of all 32 L1 blocks has published slot t   (>=t+1)
            {
                const int* p;
                int need;
                if (l < 16)      { p = flags0 + (l * 4 + w) * FSTRIDE;        need = t + 2; }
                else if (l < 48) { p = flags1 + ((l - 16) * 4 + w) * FSTRIDE; need = t + 1; }
                else             { p = flags0 + w * FSTRIDE;                  need = 0;     }
                while (true) {
                    int v = __hip_atomic_load(p, __ATOMIC_RELAXED, __HIP_MEMORY_SCOPE_AGENT);
                    if (__all(v >= need)) break;
                }
                asm volatile("" ::: "memory");
            }

            const u16* p0 = h0buf + ((size_t)(t+1) * N_B + m) * H_D + q*8;
            const u16* p1 = h1buf + ((size_t)t     * N_B + m) * H_D + q*8;
            i32x4 f[16], g[16];
            LD16X2(f, g, p0, p1);
            f32x4 accA = bv4;
            f32x4 accB = (f32x4){0.f,0.f,0.f,0.f};
            f32x4 accC = (f32x4){0.f,0.f,0.f,0.f};
            f32x4 accD = (f32x4){0.f,0.f,0.f,0.f};
            #pragma unroll
            for (int kt = 0; kt < 16; kt += 2) {
                accA = __builtin_amdgcn_mfma_f32_16x16x32_bf16(bregI[kt],   __builtin_bit_cast(short8, f[kt]),   accA, 0, 0, 0);
                accB = __builtin_amdgcn_mfma_f32_16x16x32_bf16(bregH[kt],   __builtin_bit_cast(short8, g[kt]),   accB, 0, 0, 0);
                accC = __builtin_amdgcn_mfma_f32_16x16x32_bf16(bregI[kt+1], __builtin_bit_cast(short8, f[kt+1]), accC, 0, 0, 0);
                accD = __builtin_amdgcn_mfma_f32_16x16x32_bf16(bregH[kt+1], __builtin_bit_cast(short8, g[kt+1]), accD, 0, 0, 0);
            }
            float v[4];
            #pragma unroll
            for (int r = 0; r < 4; ++r)
                v[r] = fast_tanh((accA[r] + accB[r]) + (accC[r] + accD[r]));
            i32x2 d;
            d[0] = (int)((unsigned)f2bf(v[0]) | ((unsigned)f2bf(v[1]) << 16));
            d[1] = (int)((unsigned)f2bf(v[2]) | ((unsigned)f2bf(v[3]) << 16));
            u16* hd = h1buf + (size_t)(t+1) * (N_B * H_D)
                    + (size_t)(r0 + lr) * H_D + nbase + q*4;
            asm volatile(
                "global_store_dwordx2 %1, %0, off sc1"
                :: "v"(d), "v"(hd) : "memory");
            WAITVM;
            if (l == 0) st_flag(flags1 + (c*4 + w) * FSTRIDE, t + 2);

            f32x4 ov = {v[0], v[1], v[2], v[3]};
            *(f32x4*)(out + (size_t)t * (N_B * H_D)
                      + (size_t)(r0 + lr) * H_D + nbase + q*4) = ov;
            if (t == L_SEQ - 1)
                *(f32x4*)(hn + (size_t)(N_B + r0 + lr) * H_D + nbase + q*4) = ov;
        }
    }
}

extern "C" void kernel_launch(void* const* d_in, const int* in_sizes, int n_in,
                              void* d_out, int out_size, void* d_ws, size_t ws_size,
                              hipStream_t stream)
{
    (void)in_sizes; (void)n_in; (void)out_size; (void)ws_size;
    const float* x    = (const float*)d_in[0];
    const float* h0   = (const float*)d_in[1];
    const float* w0ih = (const float*)d_in[2];
    const float* w0hh = (const float*)d_in[3];
    const float* b0i  = (const float*)d_in[4];
    const float* b0h  = (const float*)d_in[5];
    const float* w1ih = (const float*)d_in[6];
    const float* w1hh = (const float*)d_in[7];
    const float* b1i  = (const float*)d_in[8];
    const float* b1h  = (const float*)d_in[9];
    float* out = (float*)d_out;
    float* hn  = out + (size_t)M_TOT * H_D;

    char* ws = (char*)d_ws;
    size_t off = 0;
    u16* w0ihb = (u16*)(ws + off);   off += (size_t)H_D * H_D * 2;
    u16* w0hhb = (u16*)(ws + off);   off += (size_t)H_D * H_D * 2;
    u16* w1ihb = (u16*)(ws + off);   off += (size_t)H_D * H_D * 2;
    u16* w1hhb = (u16*)(ws + off);   off += (size_t)H_D * H_D * 2;
    float* bias0 = (float*)(ws + off); off += H_D * 4;
    float* bias1 = (float*)(ws + off); off += H_D * 4;
    int* flags   = (int*)(ws + off);   off += 192 * FSTRIDE * 4;
    int* flags0  = flags;                  // 64 per-(block,wave) flags
    int* flags1  = flags + 64 * FSTRIDE;   // 128 per-(block,wave) flags
    u16* h0buf   = (u16*)(ws + off);   off += (size_t)(L_SEQ + 1) * N_B * H_D * 2;
    float* pre0  = (float*)(ws + off); off += (size_t)M_TOT * H_D * 4;
    u16* h1buf   = (u16*)(ws + off);   off += (size_t)(L_SEQ + 1) * N_B * H_D * 2;
    u16* xb      = h1buf;   // xb dead after k_gemm; aliases h1buf

    k_prep<<<2048, 256, 0, stream>>>(x, w0ih, w0hh, b0i, b0h, w1ih, w1hh, b1i, b1h,
                                     xb, w0ihb, w0hhb, w1ihb, w1hhb,
                                     bias0, bias1, flags);
    k_gemm<<<dim3(M_TOT/128, H_D/128), 256, 0, stream>>>(xb, w0ihb, bias0, pre0);
    k_rec_fused<<<48, 256, 0, stream>>>(w0hhb, w1ihb, w1hhb, h0, pre0, bias1,
                                        h0buf, h1buf, out, hn, flags0, flags1);
}

// Round 7
// 2644.558 us; speedup vs baseline: 1.4667x; 1.0466x over previous
//
#include <hip/hip_runtime.h>
#include <hip/hip_bf16.h>
#include <math.h>

#define L_SEQ 512
#define N_B   64
#define H_D   512
#define M_TOT (L_SEQ * N_B)   // 32768
#define FSTRIDE 16            // one flag word per 64B line
#define SMEM_BYTES (16384 + 8 * 16384)   // 16KB h + 128KB W-tile3 = 147456

typedef unsigned short u16;
typedef unsigned long long u64;
typedef __attribute__((ext_vector_type(8))) short short8;
typedef __attribute__((ext_vector_type(4))) float f32x4;
typedef __attribute__((ext_vector_type(4))) int i32x4;
typedef __attribute__((ext_vector_type(2))) int i32x2;

__device__ __forceinline__ u16 f2bf(float f) {
    unsigned int u = __builtin_bit_cast(unsigned int, f);
    u = u + 0x7fffu + ((u >> 16) & 1u);
    return (u16)(u >> 16);
}

__device__ __forceinline__ float fast_tanh(float x) {
    float e = __expf(2.0f * x);
    return 1.0f - 2.0f / (e + 1.0f);
}

__device__ __forceinline__ void st_h(u16* p, u16 v) {
    __hip_atomic_store(p, v, __ATOMIC_RELAXED, __HIP_MEMORY_SCOPE_AGENT);
}
__device__ __forceinline__ void st_flag(int* p, int v) {
    __hip_atomic_store(p, v, __ATOMIC_RELAXED, __HIP_MEMORY_SCOPE_AGENT);
}

// 16 CACHED 16B loads (512B of one row) + single drain. (L1a h0 reads:
// write-once slots, first touch after flag; dispatch acquire kills
// cross-launch staleness.)
#define LD16(f, p)                                                          \
  asm volatile(                                                             \
    "global_load_dwordx4 %0, %16, off\n\t"                                  \
    "global_load_dwordx4 %1, %16, off offset:64\n\t"                        \
    "global_load_dwordx4 %2, %16, off offset:128\n\t"                       \
    "global_load_dwordx4 %3, %16, off offset:192\n\t"                       \
    "global_load_dwordx4 %4, %16, off offset:256\n\t"                       \
    "global_load_dwordx4 %5, %16, off offset:320\n\t"                       \
    "global_load_dwordx4 %6, %16, off offset:384\n\t"                       \
    "global_load_dwordx4 %7, %16, off offset:448\n\t"                       \
    "global_load_dwordx4 %8, %16, off offset:512\n\t"                       \
    "global_load_dwordx4 %9, %16, off offset:576\n\t"                       \
    "global_load_dwordx4 %10, %16, off offset:640\n\t"                      \
    "global_load_dwordx4 %11, %16, off offset:704\n\t"                      \
    "global_load_dwordx4 %12, %16, off offset:768\n\t"                      \
    "global_load_dwordx4 %13, %16, off offset:832\n\t"                      \
    "global_load_dwordx4 %14, %16, off offset:896\n\t"                      \
    "global_load_dwordx4 %15, %16, off offset:960\n\t"                      \
    "s_waitcnt vmcnt(0)"                                                    \
    : "=&v"(f[0]), "=&v"(f[1]), "=&v"(f[2]), "=&v"(f[3]),                   \
      "=&v"(f[4]), "=&v"(f[5]), "=&v"(f[6]), "=&v"(f[7]),                   \
      "=&v"(f[8]), "=&v"(f[9]), "=&v"(f[10]), "=&v"(f[11]),                 \
      "=&v"(f[12]), "=&v"(f[13]), "=&v"(f[14]), "=&v"(f[15])                \
    : "v"(p) : "memory")

#define WAITVM asm volatile("s_waitcnt vmcnt(0)" ::: "memory")

// h0buf position permutation within each 32-col block (unchanged from
// rounds 2-6): position p holds canonical col perm32(p).
__device__ __host__ __forceinline__ int perm32(int j) {
    return (((j >> 3) & 3) << 2) | (j & 3) | (((j >> 2) & 1) << 4);
}

// ---- prep: fp32->bf16 conversions, bias sums, flag zeroing ----
// w1ihb K-dim permuted (multiplies permuted h0buf). w0ihb, w0hhb, w1hhb
// natural (w0hhb now multiplies LDS-resident h in natural order).
__global__ void k_prep(const float* __restrict__ x,
                       const float* __restrict__ w0ih, const float* __restrict__ w0hh,
                       const float* __restrict__ b0i,  const float* __restrict__ b0h,
                       const float* __restrict__ w1ih, const float* __restrict__ w1hh,
                       const float* __restrict__ b1i,  const float* __restrict__ b1h,
                       u16* __restrict__ xb,
                       u16* __restrict__ w0ihb, u16* __restrict__ w0hhb,
                       u16* __restrict__ w1ihb, u16* __restrict__ w1hhb,
                       float* __restrict__ bias0, float* __restrict__ bias1,
                       int* __restrict__ flags)
{
    const int stride = gridDim.x * blockDim.x;
    const int tid = blockIdx.x * blockDim.x + threadIdx.x;
    for (int i = tid; i < M_TOT * H_D / 4; i += stride) {
        const float4 v = ((const float4*)x)[i];
        ushort4 o;
        o.x = f2bf(v.x); o.y = f2bf(v.y); o.z = f2bf(v.z); o.w = f2bf(v.w);
        ((ushort4*)xb)[i] = o;
    }
    for (int i = tid; i < H_D * H_D; i += stride) {
        const int p  = i & (H_D - 1);
        const int pc = (i & ~(H_D - 1)) | (p & ~31) | perm32(p & 31);
        w0ihb[i] = f2bf(w0ih[i]);
        w0hhb[i] = f2bf(w0hh[i]);
        w1ihb[i] = f2bf(w1ih[pc]);
        w1hhb[i] = f2bf(w1hh[i]);
    }
    if (tid < H_D) {
        bias0[tid] = b0i[tid] + b0h[tid];
        bias1[tid] = b1i[tid] + b1h[tid];
    }
    if (tid < 192 * FSTRIDE) flags[tid] = 0;
}

// ---- big parallel GEMM: pre0[M,512] = xb @ W0ih^T + bias0 ----
__global__ __launch_bounds__(256)
void k_gemm(const u16* __restrict__ A, const u16* __restrict__ W,
            const float* __restrict__ bias, float* __restrict__ out)
{
    __shared__ u16 As[128][40];
    __shared__ u16 Ws[128][40];
    const int m0 = blockIdx.x * 128;
    const int n0 = blockIdx.y * 128;
    const int tid = threadIdx.x;
    const int w = tid >> 6, l = tid & 63, q = l >> 4, lr = l & 15;
    const int mw = (w >> 1) * 64, nw = (w & 1) * 64;
    const int skg = (tid & 3) * 8;
    const int smr = tid >> 2;

    f32x4 acc[4][4];
    #pragma unroll
    for (int i = 0; i < 4; ++i)
        #pragma unroll
        for (int j = 0; j < 4; ++j)
            acc[i][j] = (f32x4){0.f, 0.f, 0.f, 0.f};

    for (int kk = 0; kk < H_D; kk += 32) {
        *(uint4*)&As[smr][skg]      = *(const uint4*)(A + (size_t)(m0 + smr) * H_D + kk + skg);
        *(uint4*)&As[smr + 64][skg] = *(const uint4*)(A + (size_t)(m0 + smr + 64) * H_D + kk + skg);
        *(uint4*)&Ws[smr][skg]      = *(const uint4*)(W + (size_t)(n0 + smr) * H_D + kk + skg);
        *(uint4*)&Ws[smr + 64][skg] = *(const uint4*)(W + (size_t)(n0 + smr + 64) * H_D + kk + skg);
        __syncthreads();
        short8 af[4], bf[4];
        #pragma unroll
        for (int rt = 0; rt < 4; ++rt) af[rt] = *(const short8*)&As[mw + rt*16 + lr][q*8];
        #pragma unroll
        for (int nt = 0; nt < 4; ++nt) bf[nt] = *(const short8*)&Ws[nw + nt*16 + lr][q*8];
        #pragma unroll
        for (int rt = 0; rt < 4; ++rt)
            #pragma unroll
            for (int nt = 0; nt < 4; ++nt)
                acc[rt][nt] = __builtin_amdgcn_mfma_f32_16x16x32_bf16(af[rt], bf[nt], acc[rt][nt], 0, 0, 0);
        __syncthreads();
    }
    #pragma unroll
    for (int nt = 0; nt < 4; ++nt) {
        const int col = n0 + nw + nt*16 + lr;
        const float bv = bias[col];
        #pragma unroll
        for (int rt = 0; rt < 4; ++rt) {
            #pragma unroll
            for (int r = 0; r < 4; ++r) {
                const int row = m0 + mw + rt*16 + q*4 + r;
                out[(size_t)row * H_D + col] = acc[rt][nt][r] + bv;
            }
        }
    }
}

// ---- fused recurrence: row-parallel, LDS-local recurrence loops ----
// blocks 0..3  (L0):  rows 16b..16b+16, all 512 cols of layer-0 recurrence.
//                     h lives in swizzled LDS; NO global round trip in the
//                     step chain. Publishes h0[t+1] to h0buf (sc1, lazy flag).
// blocks 4..19 (L1a): feed F[t] = h0[t+1] @ W_ih1^T + b1, streaming behind
//                     L0 (round-5 structure); F aliases pre0 (slots dead).
// blocks 20..23(L1b): rows 16b: layer-1 recurrence, h1 in LDS; F sc1-loads
//                     overlapped with the local W_hh1 MFMA; writes out/hn.
__global__ __launch_bounds__(512, 2)
void k_rec(const u16* __restrict__ Whh0, const u16* __restrict__ Wih1p,
           const u16* __restrict__ Whh1,
           const float* __restrict__ h_init,
           float* __restrict__ pre0,              // also F (aliased slots)
           const float* __restrict__ bias1,
           u16* __restrict__ h0buf,
           float* __restrict__ out, float* __restrict__ hn,
           int* __restrict__ flags)
{
    extern __shared__ char smem[];                 // [0,16K) h ; [16K,144K) W
    int* flag0 = flags;                            // 4 flags (per L0 block)
    int* flagF = flags + 16 * FSTRIDE;             // 64 flags (L1a block,wave)
    (void)__hip_atomic_load(flags, __ATOMIC_ACQUIRE, __HIP_MEMORY_SCOPE_AGENT);

    const int tid = threadIdx.x;
    const int w = tid >> 6, l = tid & 63, q = l >> 4, lr = l & 15;
    const int swz = (lr & 7) << 4;                 // h-LDS XOR swizzle (G4)
    const int blk = blockIdx.x;

    if (blk < 4) {
        // ===================== L0 recurrence =====================
        const int b = blk;
        const int R = b * 16;
        short8 bregR[16][3];                       // 48 cols in regs
        #pragma unroll
        for (int kt = 0; kt < 16; ++kt)
            #pragma unroll
            for (int nt = 0; nt < 3; ++nt)
                bregR[kt][nt] = *(const short8*)(Whh0 + (size_t)(64*w + nt*16 + lr) * H_D + kt*32 + q*8);
        char* wl = smem + 16384 + w * 16384;       // 16 cols in LDS
        #pragma unroll
        for (int kt = 0; kt < 16; ++kt) {
            short8 t3 = *(const short8*)(Whh0 + (size_t)(64*w + 48 + lr) * H_D + kt*32 + q*8);
            *(short8*)(wl + kt*1024 + (size_t)l*16) = t3;
        }
        #pragma unroll
        for (int j = 0; j < 16; ++j) {             // h_lds = h_init rows R
            int col = 64*w + q*16 + j;
            *(u16*)(smem + (((size_t)lr*1024 + col*2) ^ swz)) =
                f2bf(h_init[(R + lr) * H_D + col]);
        }
        __syncthreads();

        f32x4 pr[4];
        #pragma unroll
        for (int nt = 0; nt < 4; ++nt)
            pr[nt] = *(const f32x4*)(pre0 + (size_t)(R+lr)*H_D + 64*w + nt*16 + q*4);
        f32x4 acc[4];
        #pragma unroll
        for (int nt = 0; nt < 4; ++nt) acc[nt] = (f32x4){0.f,0.f,0.f,0.f};

        for (int t = 0; t < L_SEQ; ++t) {
            #pragma unroll
            for (int kt = 0; kt < 16; ++kt) {
                short8 hf = *(const short8*)(smem + (((size_t)lr*1024 + kt*64 + q*16) ^ swz));
                short8 wf = *(const short8*)(wl + kt*1024 + (size_t)l*16);
                acc[0] = __builtin_amdgcn_mfma_f32_16x16x32_bf16(bregR[kt][0], hf, acc[0], 0,0,0);
                acc[1] = __builtin_amdgcn_mfma_f32_16x16x32_bf16(bregR[kt][1], hf, acc[1], 0,0,0);
                acc[2] = __builtin_amdgcn_mfma_f32_16x16x32_bf16(bregR[kt][2], hf, acc[2], 0,0,0);
                acc[3] = __builtin_amdgcn_mfma_f32_16x16x32_bf16(wf,           hf, acc[3], 0,0,0);
            }
            __syncthreads();   // #1: h[t] reads done; implicit vmcnt(0)
                               //     drained slot-t stores (issued last step)
            if (tid == 0 && t > 0) st_flag(flag0 + b*FSTRIDE, t + 1);

            float v[16]; unsigned hb[16];
            #pragma unroll
            for (int nt = 0; nt < 4; ++nt)
                #pragma unroll
                for (int r = 0; r < 4; ++r) {
                    v[nt*4+r]  = fast_tanh(acc[nt][r] + pr[nt][r]);
                    hb[nt*4+r] = f2bf(v[nt*4+r]);
                }
            #pragma unroll
            for (int nt = 0; nt < 4; ++nt) {       // h_lds <- h[t+1]
                i32x2 d;
                d[0] = (int)(hb[nt*4]   | (hb[nt*4+1] << 16));
                d[1] = (int)(hb[nt*4+2] | (hb[nt*4+3] << 16));
                *(i32x2*)(smem + (((size_t)lr*1024 + (64*w + nt*16 + q*4)*2) ^ swz)) = d;
            }
            __syncthreads();   // #2: h[t+1] visible for next step

            // publish h0[t+1] to global (permuted layout; fire & forget)
            i32x4 dA, dB;
            dA[0] = (int)(hb[0]  | (hb[1]  << 16)); dA[1] = (int)(hb[2]  | (hb[3]  << 16));
            dA[2] = (int)(hb[4]  | (hb[5]  << 16)); dA[3] = (int)(hb[6]  | (hb[7]  << 16));
            dB[0] = (int)(hb[8]  | (hb[9]  << 16)); dB[1] = (int)(hb[10] | (hb[11] << 16));
            dB[2] = (int)(hb[12] | (hb[13] << 16)); dB[3] = (int)(hb[14] | (hb[15] << 16));
            u16* hd = h0buf + (size_t)(t+1)*(N_B*H_D) + (size_t)(R+lr)*H_D + 64*w + q*8;
            asm volatile("global_store_dwordx4 %2, %0, off sc1\n\t"
                         "global_store_dwordx4 %2, %1, off offset:64 sc1"
                         :: "v"(dA), "v"(dB), "v"(hd) : "memory");
            if (t == L_SEQ - 1) {
                #pragma unroll
                for (int nt = 0; nt < 4; ++nt) {
                    f32x4 o = {v[nt*4], v[nt*4+1], v[nt*4+2], v[nt*4+3]};
                    *(f32x4*)(hn + (size_t)(R+lr)*H_D + 64*w + nt*16 + q*4) = o;
                }
            }
            const int tn = (t + 1 < L_SEQ) ? t + 1 : L_SEQ - 1;
            #pragma unroll
            for (int nt = 0; nt < 4; ++nt) {
                pr[nt]  = *(const f32x4*)(pre0 + (size_t)tn*(N_B*H_D) + (size_t)(R+lr)*H_D + 64*w + nt*16 + q*4);
                acc[nt] = (f32x4){0.f,0.f,0.f,0.f};
            }
        }
        __syncthreads();                            // drains slot-512 stores
        if (tid == 0) st_flag(flag0 + b*FSTRIDE, L_SEQ + 1);
    } else if (blk < 20) {
        // ===================== L1a feed =====================
        if (w >= 4) return;                        // 4 active waves, no barriers
        const int c = blk - 4;
        const int nbase = c * 32;
        short8 breg[16][2];
        #pragma unroll
        for (int kt = 0; kt < 16; ++kt)
            #pragma unroll
            for (int nt = 0; nt < 2; ++nt)
                breg[kt][nt] = *(const short8*)(Wih1p + (size_t)(nbase + nt*16 + lr) * H_D + kt*32 + q*8);
        const f32x4 bv0 = *(const f32x4*)(bias1 + nbase + q*4);
        const f32x4 bv1 = *(const f32x4*)(bias1 + nbase + 16 + q*4);
        const int m = w*16 + lr;

        for (int t = 0; t < L_SEQ; ++t) {
            const int* p = flag0 + w*FSTRIDE;      // our rows = L0 block w
            while (true) {
                int fv = __hip_atomic_load(p, __ATOMIC_RELAXED, __HIP_MEMORY_SCOPE_AGENT);
                if (__all(fv >= t + 2)) break;
            }
            asm volatile("" ::: "memory");
            const u16* hs = h0buf + ((size_t)(t+1)*N_B + m)*H_D + q*8;
            i32x4 f[16];
            LD16(f, hs);
            f32x4 a0a = bv0, a1a = bv1;
            f32x4 a0b = (f32x4){0.f,0.f,0.f,0.f}, a1b = a0b;
            f32x4 a0c = a0b, a1c = a0b, a0d = a0b, a1d = a0b;
            #pragma unroll
            for (int kt = 0; kt < 16; kt += 4) {
                a0a = __builtin_amdgcn_mfma_f32_16x16x32_bf16(breg[kt][0],   __builtin_bit_cast(short8, f[kt]),   a0a, 0,0,0);
                a1a = __builtin_amdgcn_mfma_f32_16x16x32_bf16(breg[kt][1],   __builtin_bit_cast(short8, f[kt]),   a1a, 0,0,0);
                a0b = __builtin_amdgcn_mfma_f32_16x16x32_bf16(breg[kt+1][0], __builtin_bit_cast(short8, f[kt+1]), a0b, 0,0,0);
                a1b = __builtin_amdgcn_mfma_f32_16x16x32_bf16(breg[kt+1][1], __builtin_bit_cast(short8, f[kt+1]), a1b, 0,0,0);
                a0c = __builtin_amdgcn_mfma_f32_16x16x32_bf16(breg[kt+2][0], __builtin_bit_cast(short8, f[kt+2]), a0c, 0,0,0);
                a1c = __builtin_amdgcn_mfma_f32_16x16x32_bf16(breg[kt+2][1], __builtin_bit_cast(short8, f[kt+2]), a1c, 0,0,0);
                a0d = __builtin_amdgcn_mfma_f32_16x16x32_bf16(breg[kt+3][0], __builtin_bit_cast(short8, f[kt+3]), a0d, 0,0,0);
                a1d = __builtin_amdgcn_mfma_f32_16x16x32_bf16(breg[kt+3][1], __builtin_bit_cast(short8, f[kt+3]), a1d, 0,0,0);
            }
            f32x4 s0, s1;
            #pragma unroll
            for (int r = 0; r < 4; ++r) {
                s0[r] = (a0a[r] + a0b[r]) + (a0c[r] + a0d[r]);
                s1[r] = (a1a[r] + a1b[r]) + (a1c[r] + a1d[r]);
            }
            float* fd = pre0 + (size_t)t*(N_B*H_D) + (size_t)m*H_D + nbase + q*4;
            asm volatile("global_store_dwordx4 %2, %0, off sc1\n\t"
                         "global_store_dwordx4 %2, %1, off offset:64 sc1"
                         :: "v"(s0), "v"(s1), "v"(fd) : "memory");
            WAITVM;
            if (l == 0) st_flag(flagF + (c*4 + w)*FSTRIDE, t + 1);
        }
    } else {
        // ===================== L1b recurrence =====================
        const int b = blk - 20;
        const int R = b * 16;
        short8 bregR[16][3];
        #pragma unroll
        for (int kt = 0; kt < 16; ++kt)
            #pragma unroll
            for (int nt = 0; nt < 3; ++nt)
                bregR[kt][nt] = *(const short8*)(Whh1 + (size_t)(64*w + nt*16 + lr) * H_D + kt*32 + q*8);
        char* wl = smem + 16384 + w * 16384;
        #pragma unroll
        for (int kt = 0; kt < 16; ++kt) {
            short8 t3 = *(const short8*)(Whh1 + (size_t)(64*w + 48 + lr) * H_D + kt*32 + q*8);
            *(short8*)(wl + kt*1024 + (size_t)l*16) = t3;
        }
        const float* hi1 = h_init + N_B * H_D;
        #pragma unroll
        for (int j = 0; j < 16; ++j) {
            int col = 64*w + q*16 + j;
            *(u16*)(smem + (((size_t)lr*1024 + col*2) ^ swz)) =
                f2bf(hi1[(R + lr) * H_D + col]);
        }
        __syncthreads();

        f32x4 acc[4];
        #pragma unroll
        for (int nt = 0; nt < 4; ++nt) acc[nt] = (f32x4){0.f,0.f,0.f,0.f};

        for (int t = 0; t < L_SEQ; ++t) {
            const int* p = flagF + ((l & 15)*4 + b)*FSTRIDE;
            while (true) {
                int fv = __hip_atomic_load(p, __ATOMIC_RELAXED, __HIP_MEMORY_SCOPE_AGENT);
                if (__all(fv >= t + 1)) break;
            }
            asm volatile("" ::: "memory");
            // issue F sc1-loads; latency hides under the local MFMA loop
            const float* fp = pre0 + (size_t)t*(N_B*H_D) + (size_t)(R+lr)*H_D + 64*w + q*4;
            i32x4 fr0, fr1, fr2, fr3;
            asm volatile("global_load_dwordx4 %0, %4, off sc1\n\t"
                         "global_load_dwordx4 %1, %4, off offset:64 sc1\n\t"
                         "global_load_dwordx4 %2, %4, off offset:128 sc1\n\t"
                         "global_load_dwordx4 %3, %4, off offset:192 sc1"
                         : "=&v"(fr0), "=&v"(fr1), "=&v"(fr2), "=&v"(fr3)
                         : "v"(fp) : "memory");
            #pragma unroll
            for (int kt = 0; kt < 16; ++kt) {
                short8 hf = *(const short8*)(smem + (((size_t)lr*1024 + kt*64 + q*16) ^ swz));
                short8 wf = *(const short8*)(wl + kt*1024 + (size_t)l*16);
                acc[0] = __builtin_amdgcn_mfma_f32_16x16x32_bf16(bregR[kt][0], hf, acc[0], 0,0,0);
                acc[1] = __builtin_amdgcn_mfma_f32_16x16x32_bf16(bregR[kt][1], hf, acc[1], 0,0,0);
                acc[2] = __builtin_amdgcn_mfma_f32_16x16x32_bf16(bregR[kt][2], hf, acc[2], 0,0,0);
                acc[3] = __builtin_amdgcn_mfma_f32_16x16x32_bf16(wf,           hf, acc[3], 0,0,0);
            }
            asm volatile("s_waitcnt vmcnt(0)"
                         : "+v"(fr0), "+v"(fr1), "+v"(fr2), "+v"(fr3) :: "memory");
            f32x4 fa[4] = { __builtin_bit_cast(f32x4, fr0), __builtin_bit_cast(f32x4, fr1),
                            __builtin_bit_cast(f32x4, fr2), __builtin_bit_cast(f32x4, fr3) };
            __syncthreads();   // #1: h1[t] reads done
            float v[16]; unsigned hb[16];
            #pragma unroll
            for (int nt = 0; nt < 4; ++nt)
                #pragma unroll
                for (int r = 0; r < 4; ++r) {
                    v[nt*4+r]  = fast_tanh(fa[nt][r] + acc[nt][r]);
                    hb[nt*4+r] = f2bf(v[nt*4+r]);
                }
            #pragma unroll
            for (int nt = 0; nt < 4; ++nt) {
                i32x2 d;
                d[0] = (int)(hb[nt*4]   | (hb[nt*4+1] << 16));
                d[1] = (int)(hb[nt*4+2] | (hb[nt*4+3] << 16));
                *(i32x2*)(smem + (((size_t)lr*1024 + (64*w + nt*16 + q*4)*2) ^ swz)) = d;
            }
            #pragma unroll
            for (int nt = 0; nt < 4; ++nt) {
                f32x4 o = {v[nt*4], v[nt*4+1], v[nt*4+2], v[nt*4+3]};
                *(f32x4*)(out + (size_t)t*(N_B*H_D) + (size_t)(R+lr)*H_D + 64*w + nt*16 + q*4) = o;
                if (t == L_SEQ - 1)
                    *(f32x4*)(hn + (size_t)(N_B + R + lr)*H_D + 64*w + nt*16 + q*4) = o;
                acc[nt] = (f32x4){0.f,0.f,0.f,0.f};
            }
            __syncthreads();   // #2: h1[t+1] visible
        }
    }
}

extern "C" void kernel_launch(void* const* d_in, const int* in_sizes, int n_in,
                              void* d_out, int out_size, void* d_ws, size_t ws_size,
                              hipStream_t stream)
{
    (void)in_sizes; (void)n_in; (void)out_size; (void)ws_size;
    const float* x    = (const float*)d_in[0];
    const float* h0   = (const float*)d_in[1];
    const float* w0ih = (const float*)d_in[2];
    const float* w0hh = (const float*)d_in[3];
    const float* b0i  = (const float*)d_in[4];
    const float* b0h  = (const float*)d_in[5];
    const float* w1ih = (const float*)d_in[6];
    const float* w1hh = (const float*)d_in[7];
    const float* b1i  = (const float*)d_in[8];
    const float* b1h  = (const float*)d_in[9];
    float* out = (float*)d_out;
    float* hn  = out + (size_t)M_TOT * H_D;

    char* ws = (char*)d_ws;
    size_t off = 0;
    u16* w0ihb = (u16*)(ws + off);   off += (size_t)H_D * H_D * 2;
    u16* w0hhb = (u16*)(ws + off);   off += (size_t)H_D * H_D * 2;
    u16* w1ihb = (u16*)(ws + off);   off += (size_t)H_D * H_D * 2;
    u16* w1hhb = (u16*)(ws + off);   off += (size_t)H_D * H_D * 2;
    float* bias0 = (float*)(ws + off); off += H_D * 4;
    float* bias1 = (float*)(ws + off); off += H_D * 4;
    int* flags   = (int*)(ws + off);   off += 192 * FSTRIDE * 4;
    u16* h0buf   = (u16*)(ws + off);   off += (size_t)(L_SEQ + 1) * N_B * H_D * 2;
    float* pre0  = (float*)(ws + off); off += (size_t)M_TOT * H_D * 4;
    u16* xb      = h0buf;   // xb dead after k_gemm; h0buf slots rewritten by k_rec

    (void)hipFuncSetAttribute((const void*)k_rec,
                              hipFuncAttributeMaxDynamicSharedMemorySize, SMEM_BYTES);

    k_prep<<<2048, 256, 0, stream>>>(x, w0ih, w0hh, b0i, b0h, w1ih, w1hh, b1i, b1h,
                                     xb, w0ihb, w0hhb, w1ihb, w1hhb,
                                     bias0, bias1, flags);
    k_gemm<<<dim3(M_TOT/128, H_D/128), 256, 0, stream>>>(xb, w0ihb, bias0, pre0);
    k_rec<<<24, 512, SMEM_BYTES, stream>>>(w0hhb, w1ihb, w1hhb, h0, pre0, bias1,
                                           h0buf, out, hn, flags);
}

// Round 9
// 2630.568 us; speedup vs baseline: 1.4745x; 1.0053x over previous
//
#include <hip/hip_runtime.h>
#include <hip/hip_bf16.h>
#include <math.h>

#define L_SEQ 512
#define N_B   64
#define H_D   512
#define M_TOT (L_SEQ * N_B)   // 32768
#define FSTRIDE 16            // one flag word per 64B line
#define SMEM_BYTES (16384 + 8 * 16384)   // 16KB h + 128KB W-tile3 = 147456

typedef unsigned short u16;
typedef unsigned long long u64;
typedef __attribute__((ext_vector_type(8))) short short8;
typedef __attribute__((ext_vector_type(4))) float f32x4;
typedef __attribute__((ext_vector_type(4))) int i32x4;
typedef __attribute__((ext_vector_type(2))) int i32x2;

__device__ __forceinline__ u16 f2bf(float f) {
    unsigned int u = __builtin_bit_cast(unsigned int, f);
    u = u + 0x7fffu + ((u >> 16) & 1u);
    return (u16)(u >> 16);
}

__device__ __forceinline__ float fast_tanh(float x) {
    float e = __expf(2.0f * x);
    return 1.0f - 2.0f / (e + 1.0f);
}

__device__ __forceinline__ void st_h(u16* p, u16 v) {
    __hip_atomic_store(p, v, __ATOMIC_RELAXED, __HIP_MEMORY_SCOPE_AGENT);
}
__device__ __forceinline__ void st_flag(int* p, int v) {
    __hip_atomic_store(p, v, __ATOMIC_RELAXED, __HIP_MEMORY_SCOPE_AGENT);
}

// 16 CACHED 16B loads (512B of one row) + single drain. (L1a h0 reads:
// write-once slots, first touch after flag; dispatch acquire kills
// cross-launch staleness.)
#define LD16(f, p)                                                          \
  asm volatile(                                                             \
    "global_load_dwordx4 %0, %16, off\n\t"                                  \
    "global_load_dwordx4 %1, %16, off offset:64\n\t"                        \
    "global_load_dwordx4 %2, %16, off offset:128\n\t"                       \
    "global_load_dwordx4 %3, %16, off offset:192\n\t"                       \
    "global_load_dwordx4 %4, %16, off offset:256\n\t"                       \
    "global_load_dwordx4 %5, %16, off offset:320\n\t"                       \
    "global_load_dwordx4 %6, %16, off offset:384\n\t"                       \
    "global_load_dwordx4 %7, %16, off offset:448\n\t"                       \
    "global_load_dwordx4 %8, %16, off offset:512\n\t"                       \
    "global_load_dwordx4 %9, %16, off offset:576\n\t"                       \
    "global_load_dwordx4 %10, %16, off offset:640\n\t"                      \
    "global_load_dwordx4 %11, %16, off offset:704\n\t"                      \
    "global_load_dwordx4 %12, %16, off offset:768\n\t"                      \
    "global_load_dwordx4 %13, %16, off offset:832\n\t"                      \
    "global_load_dwordx4 %14, %16, off offset:896\n\t"                      \
    "global_load_dwordx4 %15, %16, off offset:960\n\t"                      \
    "s_waitcnt vmcnt(0)"                                                    \
    : "=&v"(f[0]), "=&v"(f[1]), "=&v"(f[2]), "=&v"(f[3]),                   \
      "=&v"(f[4]), "=&v"(f[5]), "=&v"(f[6]), "=&v"(f[7]),                   \
      "=&v"(f[8]), "=&v"(f[9]), "=&v"(f[10]), "=&v"(f[11]),                 \
      "=&v"(f[12]), "=&v"(f[13]), "=&v"(f[14]), "=&v"(f[15])                \
    : "v"(p) : "memory")

#define WAITVM asm volatile("s_waitcnt vmcnt(0)" ::: "memory")

// h0buf position permutation within each 32-col block (unchanged from
// rounds 2-7): position p holds canonical col perm32(p).
__device__ __host__ __forceinline__ int perm32(int j) {
    return (((j >> 3) & 3) << 2) | (j & 3) | (((j >> 2) & 1) << 4);
}

// ---- prep: fp32->bf16 conversions, bias sums, flag zeroing ----
// w1ihb K-dim permuted (multiplies permuted h0buf). w0ihb, w0hhb, w1hhb
// natural (w0hhb multiplies LDS-resident h in natural order).
__global__ void k_prep(const float* __restrict__ x,
                       const float* __restrict__ w0ih, const float* __restrict__ w0hh,
                       const float* __restrict__ b0i,  const float* __restrict__ b0h,
                       const float* __restrict__ w1ih, const float* __restrict__ w1hh,
                       const float* __restrict__ b1i,  const float* __restrict__ b1h,
                       u16* __restrict__ xb,
                       u16* __restrict__ w0ihb, u16* __restrict__ w0hhb,
                       u16* __restrict__ w1ihb, u16* __restrict__ w1hhb,
                       float* __restrict__ bias0, float* __restrict__ bias1,
                       int* __restrict__ flags)
{
    const int stride = gridDim.x * blockDim.x;
    const int tid = blockIdx.x * blockDim.x + threadIdx.x;
    for (int i = tid; i < M_TOT * H_D / 4; i += stride) {
        const float4 v = ((const float4*)x)[i];
        ushort4 o;
        o.x = f2bf(v.x); o.y = f2bf(v.y); o.z = f2bf(v.z); o.w = f2bf(v.w);
        ((ushort4*)xb)[i] = o;
    }
    for (int i = tid; i < H_D * H_D; i += stride) {
        const int p  = i & (H_D - 1);
        const int pc = (i & ~(H_D - 1)) | (p & ~31) | perm32(p & 31);
        w0ihb[i] = f2bf(w0ih[i]);
        w0hhb[i] = f2bf(w0hh[i]);
        w1ihb[i] = f2bf(w1ih[pc]);
        w1hhb[i] = f2bf(w1hh[i]);
    }
    if (tid < H_D) {
        bias0[tid] = b0i[tid] + b0h[tid];
        bias1[tid] = b1i[tid] + b1h[tid];
    }
    if (tid < 192 * FSTRIDE) flags[tid] = 0;
}

// ---- big parallel GEMM: pre0[M,512] = xb @ W0ih^T + bias0 ----
__global__ __launch_bounds__(256)
void k_gemm(const u16* __restrict__ A, const u16* __restrict__ W,
            const float* __restrict__ bias, float* __restrict__ out)
{
    __shared__ u16 As[128][40];
    __shared__ u16 Ws[128][40];
    const int m0 = blockIdx.x * 128;
    const int n0 = blockIdx.y * 128;
    const int tid = threadIdx.x;
    const int w = tid >> 6, l = tid & 63, q = l >> 4, lr = l & 15;
    const int mw = (w >> 1) * 64, nw = (w & 1) * 64;
    const int skg = (tid & 3) * 8;
    const int smr = tid >> 2;

    f32x4 acc[4][4];
    #pragma unroll
    for (int i = 0; i < 4; ++i)
        #pragma unroll
        for (int j = 0; j < 4; ++j)
            acc[i][j] = (f32x4){0.f, 0.f, 0.f, 0.f};

    for (int kk = 0; kk < H_D; kk += 32) {
        *(uint4*)&As[smr][skg]      = *(const uint4*)(A + (size_t)(m0 + smr) * H_D + kk + skg);
        *(uint4*)&As[smr + 64][skg] = *(const uint4*)(A + (size_t)(m0 + smr + 64) * H_D + kk + skg);
        *(uint4*)&Ws[smr][skg]      = *(const uint4*)(W + (size_t)(n0 + smr) * H_D + kk + skg);
        *(uint4*)&Ws[smr + 64][skg] = *(const uint4*)(W + (size_t)(n0 + smr + 64) * H_D + kk + skg);
        __syncthreads();
        short8 af[4], bf[4];
        #pragma unroll
        for (int rt = 0; rt < 4; ++rt) af[rt] = *(const short8*)&As[mw + rt*16 + lr][q*8];
        #pragma unroll
        for (int nt = 0; nt < 4; ++nt) bf[nt] = *(const short8*)&Ws[nw + nt*16 + lr][q*8];
        #pragma unroll
        for (int rt = 0; rt < 4; ++rt)
            #pragma unroll
            for (int nt = 0; nt < 4; ++nt)
                acc[rt][nt] = __builtin_amdgcn_mfma_f32_16x16x32_bf16(af[rt], bf[nt], acc[rt][nt], 0, 0, 0);
        __syncthreads();
    }
    #pragma unroll
    for (int nt = 0; nt < 4; ++nt) {
        const int col = n0 + nw + nt*16 + lr;
        const float bv = bias[col];
        #pragma unroll
        for (int rt = 0; rt < 4; ++rt) {
            #pragma unroll
            for (int r = 0; r < 4; ++r) {
                const int row = m0 + mw + rt*16 + q*4 + r;
                out[(size_t)row * H_D + col] = acc[rt][nt][r] + bv;
            }
        }
    }
}

// ---- fused recurrence: row-parallel, LDS-local recurrence loops ----
// blocks 0..3  (L0):  rows 16b..16b+16, all 512 cols of layer-0 recurrence.
// blocks 4..19 (L1a): feed F[t] = h0[t+1] @ W_ih1^T + b1 (writes over pre0).
// blocks 20..23(L1b): layer-1 recurrence, h1 in LDS; writes out/hn.
// waves_per_eu(2,2): pins 2 waves/SIMD -> 256-VGPR budget so the 192-reg
// weight arrays stay resident (round-7 shipped at 128 VGPR = spill = the
// measured 4.86us/step).
__global__ __attribute__((amdgpu_flat_work_group_size(512, 512), amdgpu_waves_per_eu(2, 2)))
void k_rec(const u16* __restrict__ Whh0, const u16* __restrict__ Wih1p,
           const u16* __restrict__ Whh1,
           const float* __restrict__ h_init,
           float* __restrict__ pre0,              // also F (aliased slots)
           const float* __restrict__ bias1,
           u16* __restrict__ h0buf,
           float* __restrict__ out, float* __restrict__ hn,
           int* __restrict__ flags)
{
    extern __shared__ char smem[];                 // [0,16K) h ; [16K,144K) W
    int* flag0 = flags;                            // 4 flags (per L0 block)
    int* flagF = flags + 16 * FSTRIDE;             // 64 flags (L1a block,wave)
    (void)__hip_atomic_load(flags, __ATOMIC_ACQUIRE, __HIP_MEMORY_SCOPE_AGENT);

    const int tid = threadIdx.x;
    const int w = tid >> 6, l = tid & 63, q = l >> 4, lr = l & 15;
    const int swz = (lr & 7) << 4;                 // h-LDS XOR swizzle (G4)
    const int blk = blockIdx.x;

    if (blk < 4) {
        // ===================== L0 recurrence =====================
        const int b = blk;
        const int R = b * 16;
        short8 bregR[16][3];                       // 48 cols in regs
        #pragma unroll
        for (int kt = 0; kt < 16; ++kt)
            #pragma unroll
            for (int nt = 0; nt < 3; ++nt)
                bregR[kt][nt] = *(const short8*)(Whh0 + (size_t)(64*w + nt*16 + lr) * H_D + kt*32 + q*8);
        char* wl = smem + 16384 + w * 16384;       // 16 cols in LDS
        #pragma unroll
        for (int kt = 0; kt < 16; ++kt) {
            short8 t3 = *(const short8*)(Whh0 + (size_t)(64*w + 48 + lr) * H_D + kt*32 + q*8);
            *(short8*)(wl + kt*1024 + (size_t)l*16) = t3;
        }
        #pragma unroll
        for (int j = 0; j < 16; ++j) {             // h_lds = h_init rows R
            int col = 64*w + q*16 + j;
            *(u16*)(smem + (((size_t)lr*1024 + col*2) ^ swz)) =
                f2bf(h_init[(R + lr) * H_D + col]);
        }
        __syncthreads();

        f32x4 pr[4];
        #pragma unroll
        for (int nt = 0; nt < 4; ++nt)
            pr[nt] = *(const f32x4*)(pre0 + (size_t)(R+lr)*H_D + 64*w + nt*16 + q*4);
        f32x4 acc[4];
        #pragma unroll
        for (int nt = 0; nt < 4; ++nt) acc[nt] = (f32x4){0.f,0.f,0.f,0.f};

        for (int t = 0; t < L_SEQ; ++t) {
            #pragma unroll
            for (int kt = 0; kt < 16; ++kt) {
                short8 hf = *(const short8*)(smem + (((size_t)lr*1024 + kt*64 + q*16) ^ swz));
                short8 wf = *(const short8*)(wl + kt*1024 + (size_t)l*16);
                acc[0] = __builtin_amdgcn_mfma_f32_16x16x32_bf16(bregR[kt][0], hf, acc[0], 0,0,0);
                acc[1] = __builtin_amdgcn_mfma_f32_16x16x32_bf16(bregR[kt][1], hf, acc[1], 0,0,0);
                acc[2] = __builtin_amdgcn_mfma_f32_16x16x32_bf16(bregR[kt][2], hf, acc[2], 0,0,0);
                acc[3] = __builtin_amdgcn_mfma_f32_16x16x32_bf16(wf,           hf, acc[3], 0,0,0);
            }
            __syncthreads();   // #1: h[t] reads done; implicit vmcnt(0)
                               //     drained slot-t stores (issued last step)
            if (tid == 0 && t > 0) st_flag(flag0 + b*FSTRIDE, t + 1);

            // tanh -> bf16 pack, straight into dwords (no v[]/hb[] arrays)
            i32x4 dA, dB;
            #pragma unroll
            for (int nt = 0; nt < 4; ++nt) {
                unsigned lo = (unsigned)f2bf(fast_tanh(acc[nt][0] + pr[nt][0]))
                            | ((unsigned)f2bf(fast_tanh(acc[nt][1] + pr[nt][1])) << 16);
                unsigned hi = (unsigned)f2bf(fast_tanh(acc[nt][2] + pr[nt][2]))
                            | ((unsigned)f2bf(fast_tanh(acc[nt][3] + pr[nt][3])) << 16);
                if (nt == 0)      { dA[0] = (int)lo; dA[1] = (int)hi; }
                else if (nt == 1) { dA[2] = (int)lo; dA[3] = (int)hi; }
                else if (nt == 2) { dB[0] = (int)lo; dB[1] = (int)hi; }
                else              { dB[2] = (int)lo; dB[3] = (int)hi; }
                i32x2 d; d[0] = (int)lo; d[1] = (int)hi;
                *(i32x2*)(smem + (((size_t)lr*1024 + (64*w + nt*16 + q*4)*2) ^ swz)) = d;
            }
            __syncthreads();   // #2: h[t+1] visible for next step

            // publish h0[t+1] to global (permuted layout; fire & forget)
            u16* hd = h0buf + (size_t)(t+1)*(N_B*H_D) + (size_t)(R+lr)*H_D + 64*w + q*8;
            asm volatile("global_store_dwordx4 %2, %0, off sc1\n\t"
                         "global_store_dwordx4 %2, %1, off offset:64 sc1"
                         :: "v"(dA), "v"(dB), "v"(hd) : "memory");
            if (t == L_SEQ - 1) {
                #pragma unroll
                for (int nt = 0; nt < 4; ++nt) {
                    unsigned lo = (nt < 2) ? (unsigned)dA[nt*2]     : (unsigned)dB[(nt-2)*2];
                    unsigned hi = (nt < 2) ? (unsigned)dA[nt*2 + 1] : (unsigned)dB[(nt-2)*2 + 1];
                    f32x4 o = { __builtin_bit_cast(float, lo << 16),
                                __builtin_bit_cast(float, lo & 0xffff0000u),
                                __builtin_bit_cast(float, hi << 16),
                                __builtin_bit_cast(float, hi & 0xffff0000u) };
                    *(f32x4*)(hn + (size_t)(R+lr)*H_D + 64*w + nt*16 + q*4) = o;
                }
            }
            const int tn = (t + 1 < L_SEQ) ? t + 1 : L_SEQ - 1;
            #pragma unroll
            for (int nt = 0; nt < 4; ++nt) {
                pr[nt]  = *(const f32x4*)(pre0 + (size_t)tn*(N_B*H_D) + (size_t)(R+lr)*H_D + 64*w + nt*16 + q*4);
                acc[nt] = (f32x4){0.f,0.f,0.f,0.f};
            }
        }
        __syncthreads();                            // drains slot-512 stores
        if (tid == 0) st_flag(flag0 + b*FSTRIDE, L_SEQ + 1);
    } else if (blk < 20) {
        // ===================== L1a feed =====================
        if (w >= 4) return;                        // 4 active waves, no barriers
        const int c = blk - 4;
        const int nbase = c * 32;
        short8 breg[16][2];
        #pragma unroll
        for (int kt = 0; kt < 16; ++kt)
            #pragma unroll
            for (int nt = 0; nt < 2; ++nt)
                breg[kt][nt] = *(const short8*)(Wih1p + (size_t)(nbase + nt*16 + lr) * H_D + kt*32 + q*8);
        const f32x4 bv0 = *(const f32x4*)(bias1 + nbase + q*4);
        const f32x4 bv1 = *(const f32x4*)(bias1 + nbase + 16 + q*4);
        const int m = w*16 + lr;

        for (int t = 0; t < L_SEQ; ++t) {
            const int* p = flag0 + w*FSTRIDE;      // our rows = L0 block w
            while (true) {
                int fv = __hip_atomic_load(p, __ATOMIC_RELAXED, __HIP_MEMORY_SCOPE_AGENT);
                if (__all(fv >= t + 2)) break;
            }
            asm volatile("" ::: "memory");
            const u16* hs = h0buf + ((size_t)(t+1)*N_B + m)*H_D + q*8;
            i32x4 f[16];
            LD16(f, hs);
            f32x4 a0a = bv0, a1a = bv1;
            f32x4 a0b = (f32x4){0.f,0.f,0.f,0.f}, a1b = a0b;
            f32x4 a0c = a0b, a1c = a0b, a0d = a0b, a1d = a0b;
            #pragma unroll
            for (int kt = 0; kt < 16; kt += 4) {
                a0a = __builtin_amdgcn_mfma_f32_16x16x32_bf16(breg[kt][0],   __builtin_bit_cast(short8, f[kt]),   a0a, 0,0,0);
                a1a = __builtin_amdgcn_mfma_f32_16x16x32_bf16(breg[kt][1],   __builtin_bit_cast(short8, f[kt]),   a1a, 0,0,0);
                a0b = __builtin_amdgcn_mfma_f32_16x16x32_bf16(breg[kt+1][0], __builtin_bit_cast(short8, f[kt+1]), a0b, 0,0,0);
                a1b = __builtin_amdgcn_mfma_f32_16x16x32_bf16(breg[kt+1][1], __builtin_bit_cast(short8, f[kt+1]), a1b, 0,0,0);
                a0c = __builtin_amdgcn_mfma_f32_16x16x32_bf16(breg[kt+2][0], __builtin_bit_cast(short8, f[kt+2]), a0c, 0,0,0);
                a1c = __builtin_amdgcn_mfma_f32_16x16x32_bf16(breg[kt+2][1], __builtin_bit_cast(short8, f[kt+2]), a1c, 0,0,0);
                a0d = __builtin_amdgcn_mfma_f32_16x16x32_bf16(breg[kt+3][0], __builtin_bit_cast(short8, f[kt+3]), a0d, 0,0,0);
                a1d = __builtin_amdgcn_mfma_f32_16x16x32_bf16(breg[kt+3][1], __builtin_bit_cast(short8, f[kt+3]), a1d, 0,0,0);
            }
            f32x4 s0, s1;
            #pragma unroll
            for (int r = 0; r < 4; ++r) {
                s0[r] = (a0a[r] + a0b[r]) + (a0c[r] + a0d[r]);
                s1[r] = (a1a[r] + a1b[r]) + (a1c[r] + a1d[r]);
            }
            float* fd = pre0 + (size_t)t*(N_B*H_D) + (size_t)m*H_D + nbase + q*4;
            asm volatile("global_store_dwordx4 %2, %0, off sc1\n\t"
                         "global_store_dwordx4 %2, %1, off offset:64 sc1"
                         :: "v"(s0), "v"(s1), "v"(fd) : "memory");
            WAITVM;
            if (l == 0) st_flag(flagF + (c*4 + w)*FSTRIDE, t + 1);
        }
    } else {
        // ===================== L1b recurrence =====================
        const int b = blk - 20;
        const int R = b * 16;
        short8 bregR[16][3];
        #pragma unroll
        for (int kt = 0; kt < 16; ++kt)
            #pragma unroll
            for (int nt = 0; nt < 3; ++nt)
                bregR[kt][nt] = *(const short8*)(Whh1 + (size_t)(64*w + nt*16 + lr) * H_D + kt*32 + q*8);
        char* wl = smem + 16384 + w * 16384;
        #pragma unroll
        for (int kt = 0; kt < 16; ++kt) {
            short8 t3 = *(const short8*)(Whh1 + (size_t)(64*w + 48 + lr) * H_D + kt*32 + q*8);
            *(short8*)(wl + kt*1024 + (size_t)l*16) = t3;
        }
        const float* hi1 = h_init + N_B * H_D;
        #pragma unroll
        for (int j = 0; j < 16; ++j) {
            int col = 64*w + q*16 + j;
            *(u16*)(smem + (((size_t)lr*1024 + col*2) ^ swz)) =
                f2bf(hi1[(R + lr) * H_D + col]);
        }
        __syncthreads();

        f32x4 acc[4];
        #pragma unroll
        for (int nt = 0; nt < 4; ++nt) acc[nt] = (f32x4){0.f,0.f,0.f,0.f};

        for (int t = 0; t < L_SEQ; ++t) {
            const int* p = flagF + ((l & 15)*4 + b)*FSTRIDE;
            while (true) {
                int fv = __hip_atomic_load(p, __ATOMIC_RELAXED, __HIP_MEMORY_SCOPE_AGENT);
                if (__all(fv >= t + 1)) break;
            }
            asm volatile("" ::: "memory");
            // issue F sc1-loads; latency hides under the local MFMA loop
            const float* fp = pre0 + (size_t)t*(N_B*H_D) + (size_t)(R+lr)*H_D + 64*w + q*4;
            i32x4 fr0, fr1, fr2, fr3;
            asm volatile("global_load_dwordx4 %0, %4, off sc1\n\t"
                         "global_load_dwordx4 %1, %4, off offset:64 sc1\n\t"
                         "global_load_dwordx4 %2, %4, off offset:128 sc1\n\t"
                         "global_load_dwordx4 %3, %4, off offset:192 sc1"
                         : "=&v"(fr0), "=&v"(fr1), "=&v"(fr2), "=&v"(fr3)
                         : "v"(fp) : "memory");
            #pragma unroll
            for (int kt = 0; kt < 16; ++kt) {
                short8 hf = *(const short8*)(smem + (((size_t)lr*1024 + kt*64 + q*16) ^ swz));
                short8 wf = *(const short8*)(wl + kt*1024 + (size_t)l*16);
                acc[0] = __builtin_amdgcn_mfma_f32_16x16x32_bf16(bregR[kt][0], hf, acc[0], 0,0,0);
                acc[1] = __builtin_amdgcn_mfma_f32_16x16x32_bf16(bregR[kt][1], hf, acc[1], 0,0,0);
                acc[2] = __builtin_amdgcn_mfma_f32_16x16x32_bf16(bregR[kt][2], hf, acc[2], 0,0,0);
                acc[3] = __builtin_amdgcn_mfma_f32_16x16x32_bf16(wf,           hf, acc[3], 0,0,0);
            }
            asm volatile("s_waitcnt vmcnt(0)"
                         : "+v"(fr0), "+v"(fr1), "+v"(fr2), "+v"(fr3) :: "memory");
            f32x4 fa[4] = { __builtin_bit_cast(f32x4, fr0), __builtin_bit_cast(f32x4, fr1),
                            __builtin_bit_cast(f32x4, fr2), __builtin_bit_cast(f32x4, fr3) };
            __syncthreads();   // #1: h1[t] reads done
            #pragma unroll
            for (int nt = 0; nt < 4; ++nt) {
                f32x4 o;
                o[0] = fast_tanh(fa[nt][0] + acc[nt][0]);
                o[1] = fast_tanh(fa[nt][1] + acc[nt][1]);
                o[2] = fast_tanh(fa[nt][2] + acc[nt][2]);
                o[3] = fast_tanh(fa[nt][3] + acc[nt][3]);
                *(f32x4*)(out + (size_t)t*(N_B*H_D) + (size_t)(R+lr)*H_D + 64*w + nt*16 + q*4) = o;
                if (t == L_SEQ - 1)
                    *(f32x4*)(hn + (size_t)(N_B + R + lr)*H_D + 64*w + nt*16 + q*4) = o;
                i32x2 d;
                d[0] = (int)((unsigned)f2bf(o[0]) | ((unsigned)f2bf(o[1]) << 16));
                d[1] = (int)((unsigned)f2bf(o[2]) | ((unsigned)f2bf(o[3]) << 16));
                *(i32x2*)(smem + (((size_t)lr*1024 + (64*w + nt*16 + q*4)*2) ^ swz)) = d;
                acc[nt] = (f32x4){0.f,0.f,0.f,0.f};
            }
            __syncthreads();   // #2: h1[t+1] visible
        }
    }
}

extern "C" void kernel_launch(void* const* d_in, const int* in_sizes, int n_in,
                              void* d_out, int out_size, void* d_ws, size_t ws_size,
                              hipStream_t stream)
{
    (void)in_sizes; (void)n_in; (void)out_size; (void)ws_size;
    const float* x    = (const float*)d_in[0];
    const float* h0   = (const float*)d_in[1];
    const float* w0ih = (const float*)d_in[2];
    const float* w0hh = (const float*)d_in[3];
    const float* b0i  = (const float*)d_in[4];
    const float* b0h  = (const float*)d_in[5];
    const float* w1ih = (const float*)d_in[6];
    const float* w1hh = (const float*)d_in[7];
    const float* b1i  = (const float*)d_in[8];
    const float* b1h  = (const float*)d_in[9];
    float* out = (float*)d_out;
    float* hn  = out + (size_t)M_TOT * H_D;

    char* ws = (char*)d_ws;
    size_t off = 0;
    u16* w0ihb = (u16*)(ws + off);   off += (size_t)H_D * H_D * 2;
    u16* w0hhb = (u16*)(ws + off);   off += (size_t)H_D * H_D * 2;
    u16* w1ihb = (u16*)(ws + off);   off += (size_t)H_D * H_D * 2;
    u16* w1hhb = (u16*)(ws + off);   off += (size_t)H_D * H_D * 2;
    float* bias0 = (float*)(ws + off); off += H_D * 4;
    float* bias1 = (float*)(ws + off); off += H_D * 4;
    int* flags   = (int*)(ws + off);   off += 192 * FSTRIDE * 4;
    u16* h0buf   = (u16*)(ws + off);   off += (size_t)(L_SEQ + 1) * N_B * H_D * 2;
    float* pre0  = (float*)(ws + off); off += (size_t)M_TOT * H_D * 4;
    u16* xb      = h0buf;   // xb dead after k_gemm; h0buf slots rewritten by k_rec

    (void)hipFuncSetAttribute((const void*)k_rec,
                              hipFuncAttributeMaxDynamicSharedMemorySize, SMEM_BYTES);

    k_prep<<<2048, 256, 0, stream>>>(x, w0ih, w0hh, b0i, b0h, w1ih, w1hh, b1i, b1h,
                                     xb, w0ihb, w0hhb, w1ihb, w1hhb,
                                     bias0, bias1, flags);
    k_gemm<<<dim3(M_TOT/128, H_D/128), 256, 0, stream>>>(xb, w0ihb, bias0, pre0);
    k_rec<<<24, 512, SMEM_BYTES, stream>>>(w0hhb, w1ihb, w1hhb, h0, pre0, bias1,
                                           h0buf, out, hn, flags);
}